// Round 5
// baseline (263.954 us; speedup 1.0000x reference)
//
#include <hip/hip_runtime.h>

#define SEQ   1024
#define HEADS 12
#define CDIM  768
#define BATCH 8

// 0.125 * log2(e): folds the 1/sqrt(64) score scale and the exp->exp2 change
#define QSCALE 0.18033688011112042f

typedef __attribute__((ext_vector_type(8))) short bf16x8;
typedef __attribute__((ext_vector_type(4))) float f32x4;
typedef __attribute__((ext_vector_type(4))) float float4v;
typedef __attribute__((ext_vector_type(4))) short short4v;

__device__ __forceinline__ void gload_lds16(const void* g, void* l) {
  __builtin_amdgcn_global_load_lds(
      (const __attribute__((address_space(1))) unsigned int*)g,
      (__attribute__((address_space(3))) unsigned int*)l, 16, 0, 0);
}

__device__ __forceinline__ unsigned short f2bf(float f) {
  union { float f; unsigned u; } v; v.f = f;
  unsigned r = v.u + 0x7fff + ((v.u >> 16) & 1);
  return (unsigned short)(r >> 16);
}

// pack two f32 -> u32 of 2x bf16 (lo = a, hi = b); no builtin on gfx950
__device__ __forceinline__ unsigned cvtpk(float a, float b) {
  unsigned r;
  asm("v_cvt_pk_bf16_f32 %0, %1, %2" : "=v"(r) : "v"(a), "v"(b));
  return r;
}

// pinned-issue pos prefetch: 4x dwordx4 = 16 f32 (one 16-kv strip x4 t-groups)
#define POSLOAD(d, addr)                                              \
  asm volatile("global_load_dwordx4 %0, %4, off\n\t"                  \
               "global_load_dwordx4 %1, %4, off offset:64\n\t"        \
               "global_load_dwordx4 %2, %4, off offset:128\n\t"       \
               "global_load_dwordx4 %3, %4, off offset:192"           \
               : "=&v"(d[0]), "=&v"(d[1]), "=&v"(d[2]), "=&v"(d[3])   \
               : "v"(addr))

// x [8192,768] f32 -> A [8192,768] bf16
__global__ __launch_bounds__(256) void prep_x_kernel(const float* __restrict__ x,
                                                     short* __restrict__ A) {
  int i = blockIdx.x * 256 + threadIdx.x;
  int r = i / 192;
  int c4 = (i % 192) * 4;
  float4v xv = *(const float4v*)(x + (size_t)r * 768 + c4);
  short4v hi;
#pragma unroll
  for (int j = 0; j < 4; ++j) hi[j] = (short)f2bf(xv[j]);
  *(short4v*)(A + (size_t)r * 768 + c4) = hi;
}

// W_qkv [768,2304] f32 -> Bt [2304,768] bf16 transposed
__global__ __launch_bounds__(256) void prep_w_kernel(const float* __restrict__ W,
                                                     short* __restrict__ Bt) {
  __shared__ float tile[64][65];
  int k0 = blockIdx.x * 64;
  int n0 = blockIdx.y * 64;
  int t = threadIdx.x;
#pragma unroll
  for (int it = 0; it < 16; ++it) {
    int r = it * 4 + (t >> 6);
    int c = t & 63;
    tile[r][c] = W[(size_t)(k0 + r) * 2304 + n0 + c];
  }
  __syncthreads();
#pragma unroll
  for (int it = 0; it < 16; ++it) {
    int nr = it * 4 + (t >> 6);
    int kc = t & 63;
    Bt[(size_t)(n0 + nr) * 768 + k0 + kc] = (short)f2bf(tile[kc][nr]);
  }
}

// W_proj [768,768] f32 -> Wpt [768,768] bf16 transposed
__global__ __launch_bounds__(256) void prep_wp_kernel(const float* __restrict__ W,
                                                      short* __restrict__ Bt) {
  __shared__ float tile[64][65];
  int k0 = blockIdx.x * 64;
  int n0 = blockIdx.y * 64;
  int t = threadIdx.x;
#pragma unroll
  for (int it = 0; it < 16; ++it) {
    int r = it * 4 + (t >> 6);
    int c = t & 63;
    tile[r][c] = W[(size_t)(k0 + r) * 768 + n0 + c];
  }
  __syncthreads();
#pragma unroll
  for (int it = 0; it < 16; ++it) {
    int nr = it * 4 + (t >> 6);
    int kc = t & 63;
    Bt[(size_t)(n0 + nr) * 768 + k0 + kc] = (short)f2bf(tile[kc][nr]);
  }
}

// Shared 128x128-tile GEMM, BK=64, K=768, 4 waves, 16x16x32 bf16 MFMA.
template <int MODE>
__global__ __launch_bounds__(256) void gemm_kernel(
    const short* __restrict__ A, const short* __restrict__ Bt,
    const float* __restrict__ bias,
    short* __restrict__ outQ, short* __restrict__ outK, short* __restrict__ outVT,
    float* __restrict__ outF) {
  const int n0 = blockIdx.x * 128;
  const int m0 = blockIdx.y * 128;
  __shared__ short Als[128 * 64];
  __shared__ short Bls[128 * 64];
  const int tid = threadIdx.x;
  const int lane = tid & 63;
  const int w = tid >> 6;
  const int wr = (w >> 1) * 64;
  const int wc = (w & 1) * 64;
  f32x4 acc[4][4];
#pragma unroll
  for (int mi = 0; mi < 4; ++mi)
#pragma unroll
    for (int ni = 0; ni < 4; ++ni) acc[mi][ni] = (f32x4){0.f, 0.f, 0.f, 0.f};

  for (int k0 = 0; k0 < 768; k0 += 64) {
#pragma unroll
    for (int it = 0; it < 4; ++it) {
      int rbase = it * 32 + w * 8;
      int row = rbase + (lane >> 3);
      int ul = (lane & 7) ^ (row & 7);
      gload_lds16(A + (size_t)(m0 + row) * 768 + k0 + ul * 8, Als + rbase * 64);
      gload_lds16(Bt + (size_t)(n0 + row) * 768 + k0 + ul * 8, Bls + rbase * 64);
    }
    __syncthreads();
#pragma unroll
    for (int kk = 0; kk < 2; ++kk) {
      bf16x8 af[4], bfv[4];
#pragma unroll
      for (int mi = 0; mi < 4; ++mi) {
        int row = wr + mi * 16 + (lane & 15);
        int off = (row * 128 + kk * 64 + (lane >> 4) * 16) ^ ((row & 7) << 4);
        af[mi] = *(const bf16x8*)((const char*)Als + off);
      }
#pragma unroll
      for (int ni = 0; ni < 4; ++ni) {
        int row = wc + ni * 16 + (lane & 15);
        int off = (row * 128 + kk * 64 + (lane >> 4) * 16) ^ ((row & 7) << 4);
        bfv[ni] = *(const bf16x8*)((const char*)Bls + off);
      }
#pragma unroll
      for (int mi = 0; mi < 4; ++mi)
#pragma unroll
        for (int ni = 0; ni < 4; ++ni)
          acc[mi][ni] = __builtin_amdgcn_mfma_f32_16x16x32_bf16(
              af[mi], bfv[ni], acc[mi][ni], 0, 0, 0);
    }
    __syncthreads();
  }
#pragma unroll
  for (int mi = 0; mi < 4; ++mi)
#pragma unroll
    for (int ni = 0; ni < 4; ++ni)
#pragma unroll
      for (int j = 0; j < 4; ++j) {
        int row = m0 + wr + mi * 16 + ((lane >> 4) << 2) + j;
        int col = n0 + wc + ni * 16 + (lane & 15);
        float v = acc[mi][ni][j] + bias[col];
        if (MODE == 1) {
          int three = col / 768;
          int rem = col - three * 768;
          int h = rem >> 6, d = rem & 63;
          int b = row >> 10, n = row & 1023;
          size_t bh = (size_t)(b * 12 + h);
          if (three == 0)      outQ[(bh * 1024 + n) * 64 + d] = (short)f2bf(v * QSCALE);
          else if (three == 1) outK[(bh * 1024 + n) * 64 + d] = (short)f2bf(v);
          else                 outVT[(bh * 64 + d) * 1024 + n] = (short)f2bf(v);
        } else {
          outF[(size_t)row * 768 + col] = v;
        }
      }
}

// Flash attention, swapped-operand QK^T, fixed-shift softmax, 8 waves x 16 q,
// distance-2 pipeline: 3 LDS buffers, counted vmcnt (exactly 6 vmem/tile:
// 4 asm pos loads + 2 global_load_lds), one barrier per tile, no drains.
__global__ __launch_bounds__(512) void attn_kernel(
    const short* __restrict__ qb, const short* __restrict__ kb,
    const short* __restrict__ vtb, const float* __restrict__ pos,
    short* __restrict__ outb) {
  // XCD swizzle: 768 % 8 == 0, 96 consecutive logical blocks per XCD
  const int bid = blockIdx.x;
  const int lb = (bid & 7) * 96 + (bid >> 3);
  const int qblk = lb & 7;
  const int bhid = lb >> 3;
  const int h = bhid % 12, b = bhid / 12;

  const int tid = threadIdx.x, lane = tid & 63, w = tid >> 6;
  const int c = lane & 15, g = lane >> 4;
  const size_t bh = (size_t)(b * 12 + h);
  const short* Q = qb + bh * SEQ * 64;
  const short* K = kb + bh * SEQ * 64;
  const short* VT = vtb + bh * 64 * SEQ;
  const float* Ph = pos + (size_t)h * SEQ * SEQ;
  const int q0w = qblk * 128 + w * 16;

  __shared__ short kls[3 * 4096];
  __shared__ short vls[3 * 4096];

  // Q as B-operand: col = q = c, k-dim = d; Q pre-scaled by QSCALE.
  bf16x8 qf0 = *(const bf16x8*)(Q + (size_t)(q0w + c) * 64 + g * 8);
  bf16x8 qf1 = *(const bf16x8*)(Q + (size_t)(q0w + c) * 64 + 32 + g * 8);

  const float* pbase = Ph + (size_t)(q0w + c) * SEQ + g * 4;

  f32x4 o[4];   // O^T accum: d = t2*16 + g*4 + j, q = c
#pragma unroll
  for (int t2 = 0; t2 < 4; ++t2) o[t2] = (f32x4){0.f, 0.f, 0.f, 0.f};
  float lsum = 0.f;          // per-lane partial; cross-lane reduced at end
  f32x4 pc[4], pn[4];

  // 8-wave STAGE: each thread 1 K-load + 1 V-load; wave w covers rows 8w..8w+7
  auto STAGE = [&](int buf, int kv0) {
    int row = w * 8 + (lane >> 3);
    int ul = (lane & 7) ^ (row & 7);
    gload_lds16(K + (size_t)(kv0 + row) * 64 + ul * 8, kls + buf * 4096 + w * 512);
    gload_lds16(VT + (size_t)row * SEQ + kv0 + ul * 8, vls + buf * 4096 + w * 512);
  };

  // prologue: issue order = stage(0)[2], stage(1)[2], pos(0)[4]
  STAGE(0, 0);
  STAGE(1, 64);
  POSLOAD(pc, pbase);
  // newest 6 = {stage(1), pos(0)} -> stage(0) landed
  asm volatile("s_waitcnt vmcnt(6)" ::: "memory");
  __builtin_amdgcn_sched_barrier(0);
  __builtin_amdgcn_s_barrier();

#pragma unroll
  for (int ti = 0; ti < 16; ++ti) {
    const int kv0 = ti * 64;
    if (ti < 15) POSLOAD(pn, pbase + (ti + 1) * 64);
    if (ti < 14) STAGE((ti + 2) % 3, kv0 + 128);

    // counted wait: guarantee pos(ti) and stage(ti+1) landed (all older than
    // this tile's issues). 6 issued when ti<14, 4 at ti==14, 0 at ti==15.
    if (ti < 14)       asm volatile("s_waitcnt vmcnt(6)" ::: "memory");
    else if (ti == 14) asm volatile("s_waitcnt vmcnt(4)" ::: "memory");
    else               asm volatile("s_waitcnt vmcnt(0)" ::: "memory");
    __builtin_amdgcn_sched_barrier(0);

    const short* kc = kls + (ti % 3) * 4096;
    const short* vc = vls + (ti % 3) * 4096;

    // QK^T swapped: A = K (rows = kv), B = Q (cols = q).
    f32x4 s[4];
    __builtin_amdgcn_s_setprio(1);
#pragma unroll
    for (int t = 0; t < 4; ++t) {
      int row = t * 16 + c;
      int sw = (row & 7) << 4;
      bf16x8 kf0 = *(const bf16x8*)((const char*)kc + ((row * 128 + g * 16) ^ sw));
      bf16x8 kf1 = *(const bf16x8*)((const char*)kc + ((row * 128 + 64 + g * 16) ^ sw));
      f32x4 z = (f32x4){0.f, 0.f, 0.f, 0.f};
      z = __builtin_amdgcn_mfma_f32_16x16x32_bf16(kf0, qf0, z, 0, 0, 0);
      s[t] = __builtin_amdgcn_mfma_f32_16x16x32_bf16(kf1, qf1, z, 0, 0, 0);
    }
    __builtin_amdgcn_s_setprio(0);

    // P = exp2(qk + pos*QSCALE) directly — no max subtraction needed
#pragma unroll
    for (int t = 0; t < 4; ++t)
#pragma unroll
      for (int j = 0; j < 4; ++j) {
        float p = exp2f(fmaf(pc[t][j], QSCALE, s[t][j]));
        s[t][j] = p;
        lsum += p;
      }

    // pack P^T to bf16 pairs
    unsigned pk00 = cvtpk(s[0][0], s[0][1]), pk01 = cvtpk(s[0][2], s[0][3]);
    unsigned pk10 = cvtpk(s[1][0], s[1][1]), pk11 = cvtpk(s[1][2], s[1][3]);
    unsigned pk20 = cvtpk(s[2][0], s[2][1]), pk21 = cvtpk(s[2][2], s[2][3]);
    unsigned pk30 = cvtpk(s[3][0], s[3][1]), pk31 = cvtpk(s[3][2], s[3][3]);

    // redistribute to PV B-frags: lane needs kv = m*32 + g*8 + i (i=0..7)
    int src0 = ((g * 2) & 3) * 16 + c;
    int src1 = src0 + 16;
    int hi = g >> 1;
    union { bf16x8 v; unsigned u[4]; } pb0, pb1;
    {
      unsigned a0 = (unsigned)__shfl((int)pk00, src0), b0 = (unsigned)__shfl((int)pk10, src0);
      unsigned a1 = (unsigned)__shfl((int)pk01, src0), b1 = (unsigned)__shfl((int)pk11, src0);
      unsigned a2 = (unsigned)__shfl((int)pk00, src1), b2 = (unsigned)__shfl((int)pk10, src1);
      unsigned a3 = (unsigned)__shfl((int)pk01, src1), b3 = (unsigned)__shfl((int)pk11, src1);
      pb0.u[0] = hi ? b0 : a0; pb0.u[1] = hi ? b1 : a1;
      pb0.u[2] = hi ? b2 : a2; pb0.u[3] = hi ? b3 : a3;
    }
    {
      unsigned a0 = (unsigned)__shfl((int)pk20, src0), b0 = (unsigned)__shfl((int)pk30, src0);
      unsigned a1 = (unsigned)__shfl((int)pk21, src0), b1 = (unsigned)__shfl((int)pk31, src0);
      unsigned a2 = (unsigned)__shfl((int)pk20, src1), b2 = (unsigned)__shfl((int)pk30, src1);
      unsigned a3 = (unsigned)__shfl((int)pk21, src1), b3 = (unsigned)__shfl((int)pk31, src1);
      pb1.u[0] = hi ? b0 : a0; pb1.u[1] = hi ? b1 : a1;
      pb1.u[2] = hi ? b2 : a2; pb1.u[3] = hi ? b3 : a3;
    }

    // PV: O^T += V^T(rows=d) x P^T(cols=q)
    __builtin_amdgcn_s_setprio(1);
#pragma unroll
    for (int t2 = 0; t2 < 4; ++t2) {
      int rv = t2 * 16 + c;
      int swv = (rv & 7) << 4;
      bf16x8 vf0 = *(const bf16x8*)((const char*)vc + ((rv * 128 + g * 16) ^ swv));
      bf16x8 vf1 = *(const bf16x8*)((const char*)vc + ((rv * 128 + 64 + g * 16) ^ swv));
      o[t2] = __builtin_amdgcn_mfma_f32_16x16x32_bf16(vf0, pb0.v, o[t2], 0, 0, 0);
      o[t2] = __builtin_amdgcn_mfma_f32_16x16x32_bf16(vf1, pb1.v, o[t2], 0, 0, 0);
    }
    __builtin_amdgcn_s_setprio(0);

#pragma unroll
    for (int t = 0; t < 4; ++t) pc[t] = pn[t];

    if (ti < 15) __builtin_amdgcn_s_barrier();
  }

  // deferred cross-lane lsum reduction (q-column group {c, c+16, c+32, c+48})
  lsum += __shfl_xor(lsum, 16);
  lsum += __shfl_xor(lsum, 32);
  float inv = 1.0f / lsum;
  size_t obase = (size_t)(b * SEQ + q0w + c) * 768 + h * 64;
#pragma unroll
  for (int t2 = 0; t2 < 4; ++t2) {
    short4v ov;
#pragma unroll
    for (int j = 0; j < 4; ++j) ov[j] = (short)f2bf(o[t2][j] * inv);
    *(short4v*)(outb + obase + t2 * 16 + g * 4) = ov;
  }
}

extern "C" void kernel_launch(void* const* d_in, const int* in_sizes, int n_in,
                              void* d_out, int out_size, void* d_ws, size_t ws_size,
                              hipStream_t stream) {
  const float* x      = (const float*)d_in[0];
  const float* pos    = (const float*)d_in[1];
  const float* W_qkv  = (const float*)d_in[2];
  const float* b_qkv  = (const float*)d_in[3];
  const float* W_proj = (const float*)d_in[4];
  const float* b_proj = (const float*)d_in[5];
  float* out = (float*)d_out;

  char* ws = (char*)d_ws;
  short* A       = (short*)(ws);                  // 12,582,912 (consumed by gemm<1>)
  short* attnbuf = (short*)(ws);                  // alias of A (written after)
  short* Bt      = (short*)(ws + 12582912);       //  3,538,944
  short* wpt     = (short*)(ws + 16121856);       //  1,179,648
  short* qbuf    = (short*)(ws + 17301504);       // 12,582,912
  short* kbuf    = (short*)(ws + 29884416);       // 12,582,912
  short* vtbuf   = (short*)(ws + 42467328);       // 12,582,912
  // total: 55,050,240 bytes

  prep_x_kernel<<<6144, 256, 0, stream>>>(x, A);
  prep_w_kernel<<<dim3(12, 36), 256, 0, stream>>>(W_qkv, Bt);
  prep_wp_kernel<<<dim3(12, 12), 256, 0, stream>>>(W_proj, wpt);
  gemm_kernel<1><<<dim3(18, 64), 256, 0, stream>>>(A, Bt, b_qkv,
                                                   qbuf, kbuf, vtbuf, nullptr);
  attn_kernel<<<768, 512, 0, stream>>>(qbuf, kbuf, vtbuf, pos, attnbuf);
  gemm_kernel<2><<<dim3(6, 64), 256, 0, stream>>>(attnbuf, wpt, b_proj,
                                                  nullptr, nullptr, nullptr, out);
}

// Round 6
// 188.547 us; speedup vs baseline: 1.3999x; 1.3999x over previous
//
#include <hip/hip_runtime.h>

#define SEQ   1024
#define HEADS 12
#define CDIM  768
#define BATCH 8

// 0.125 * log2(e): folds the 1/sqrt(64) score scale and the exp->exp2 change
#define QSCALE 0.18033688011112042f

typedef __attribute__((ext_vector_type(8))) short bf16x8;
typedef __attribute__((ext_vector_type(4))) float f32x4;
typedef __attribute__((ext_vector_type(4))) float float4v;
typedef __attribute__((ext_vector_type(4))) short short4v;

__device__ __forceinline__ void gload_lds16(const void* g, void* l) {
  __builtin_amdgcn_global_load_lds(
      (const __attribute__((address_space(1))) unsigned int*)g,
      (__attribute__((address_space(3))) unsigned int*)l, 16, 0, 0);
}

__device__ __forceinline__ unsigned short f2bf(float f) {
  union { float f; unsigned u; } v; v.f = f;
  unsigned r = v.u + 0x7fff + ((v.u >> 16) & 1);
  return (unsigned short)(r >> 16);
}

// pack two f32 -> u32 of 2x bf16 (lo = a, hi = b); no builtin on gfx950
__device__ __forceinline__ unsigned cvtpk(float a, float b) {
  unsigned r;
  asm("v_cvt_pk_bf16_f32 %0, %1, %2" : "=v"(r) : "v"(a), "v"(b));
  return r;
}

// x [8192,768] f32 -> A [8192,768] bf16
__global__ __launch_bounds__(256) void prep_x_kernel(const float* __restrict__ x,
                                                     short* __restrict__ A) {
  int i = blockIdx.x * 256 + threadIdx.x;
  int r = i / 192;
  int c4 = (i % 192) * 4;
  float4v xv = *(const float4v*)(x + (size_t)r * 768 + c4);
  short4v hi;
#pragma unroll
  for (int j = 0; j < 4; ++j) hi[j] = (short)f2bf(xv[j]);
  *(short4v*)(A + (size_t)r * 768 + c4) = hi;
}

// W_qkv [768,2304] f32 -> Bt [2304,768] bf16 transposed
__global__ __launch_bounds__(256) void prep_w_kernel(const float* __restrict__ W,
                                                     short* __restrict__ Bt) {
  __shared__ float tile[64][65];
  int k0 = blockIdx.x * 64;
  int n0 = blockIdx.y * 64;
  int t = threadIdx.x;
#pragma unroll
  for (int it = 0; it < 16; ++it) {
    int r = it * 4 + (t >> 6);
    int c = t & 63;
    tile[r][c] = W[(size_t)(k0 + r) * 2304 + n0 + c];
  }
  __syncthreads();
#pragma unroll
  for (int it = 0; it < 16; ++it) {
    int nr = it * 4 + (t >> 6);
    int kc = t & 63;
    Bt[(size_t)(n0 + nr) * 768 + k0 + kc] = (short)f2bf(tile[kc][nr]);
  }
}

// W_proj [768,768] f32 -> Wpt [768,768] bf16 transposed
__global__ __launch_bounds__(256) void prep_wp_kernel(const float* __restrict__ W,
                                                      short* __restrict__ Bt) {
  __shared__ float tile[64][65];
  int k0 = blockIdx.x * 64;
  int n0 = blockIdx.y * 64;
  int t = threadIdx.x;
#pragma unroll
  for (int it = 0; it < 16; ++it) {
    int r = it * 4 + (t >> 6);
    int c = t & 63;
    tile[r][c] = W[(size_t)(k0 + r) * 768 + n0 + c];
  }
  __syncthreads();
#pragma unroll
  for (int it = 0; it < 16; ++it) {
    int nr = it * 4 + (t >> 6);
    int kc = t & 63;
    Bt[(size_t)(n0 + nr) * 768 + k0 + kc] = (short)f2bf(tile[kc][nr]);
  }
}

// Shared 128x128-tile GEMM, BK=64, K=768, 4 waves, 16x16x32 bf16 MFMA.
template <int MODE>
__global__ __launch_bounds__(256) void gemm_kernel(
    const short* __restrict__ A, const short* __restrict__ Bt,
    const float* __restrict__ bias,
    short* __restrict__ outQ, short* __restrict__ outK, short* __restrict__ outVT,
    float* __restrict__ outF) {
  const int n0 = blockIdx.x * 128;
  const int m0 = blockIdx.y * 128;
  __shared__ short Als[128 * 64];
  __shared__ short Bls[128 * 64];
  const int tid = threadIdx.x;
  const int lane = tid & 63;
  const int w = tid >> 6;
  const int wr = (w >> 1) * 64;
  const int wc = (w & 1) * 64;
  f32x4 acc[4][4];
#pragma unroll
  for (int mi = 0; mi < 4; ++mi)
#pragma unroll
    for (int ni = 0; ni < 4; ++ni) acc[mi][ni] = (f32x4){0.f, 0.f, 0.f, 0.f};

  for (int k0 = 0; k0 < 768; k0 += 64) {
#pragma unroll
    for (int it = 0; it < 4; ++it) {
      int rbase = it * 32 + w * 8;
      int row = rbase + (lane >> 3);
      int ul = (lane & 7) ^ (row & 7);
      gload_lds16(A + (size_t)(m0 + row) * 768 + k0 + ul * 8, Als + rbase * 64);
      gload_lds16(Bt + (size_t)(n0 + row) * 768 + k0 + ul * 8, Bls + rbase * 64);
    }
    __syncthreads();
#pragma unroll
    for (int kk = 0; kk < 2; ++kk) {
      bf16x8 af[4], bfv[4];
#pragma unroll
      for (int mi = 0; mi < 4; ++mi) {
        int row = wr + mi * 16 + (lane & 15);
        int off = (row * 128 + kk * 64 + (lane >> 4) * 16) ^ ((row & 7) << 4);
        af[mi] = *(const bf16x8*)((const char*)Als + off);
      }
#pragma unroll
      for (int ni = 0; ni < 4; ++ni) {
        int row = wc + ni * 16 + (lane & 15);
        int off = (row * 128 + kk * 64 + (lane >> 4) * 16) ^ ((row & 7) << 4);
        bfv[ni] = *(const bf16x8*)((const char*)Bls + off);
      }
#pragma unroll
      for (int mi = 0; mi < 4; ++mi)
#pragma unroll
        for (int ni = 0; ni < 4; ++ni)
          acc[mi][ni] = __builtin_amdgcn_mfma_f32_16x16x32_bf16(
              af[mi], bfv[ni], acc[mi][ni], 0, 0, 0);
    }
    __syncthreads();
  }
#pragma unroll
  for (int mi = 0; mi < 4; ++mi)
#pragma unroll
    for (int ni = 0; ni < 4; ++ni)
#pragma unroll
      for (int j = 0; j < 4; ++j) {
        int row = m0 + wr + mi * 16 + ((lane >> 4) << 2) + j;
        int col = n0 + wc + ni * 16 + (lane & 15);
        float v = acc[mi][ni][j] + bias[col];
        if (MODE == 1) {
          int three = col / 768;
          int rem = col - three * 768;
          int h = rem >> 6, d = rem & 63;
          int b = row >> 10, n = row & 1023;
          size_t bh = (size_t)(b * 12 + h);
          if (three == 0)      outQ[(bh * 1024 + n) * 64 + d] = (short)f2bf(v * QSCALE);
          else if (three == 1) outK[(bh * 1024 + n) * 64 + d] = (short)f2bf(v);
          else                 outVT[(bh * 64 + d) * 1024 + n] = (short)f2bf(v);
        } else {
          outF[(size_t)row * 768 + col] = v;
        }
      }
}

// Flash attention, swapped-operand QK^T, fixed-shift softmax, 8 waves x 16 q.
// Distance-2 staging over 3 LDS buffers; counted vmcnt(6) placed BEFORE the
// per-tile barrier (each wave proves its own stage(ti+1) landed before the
// barrier publishes the buffer); pos prefetched one tile ahead into registers
// by plain compiler loads (no asm, no full unroll -> no spills).
__global__ __launch_bounds__(512) void attn_kernel(
    const short* __restrict__ qb, const short* __restrict__ kb,
    const short* __restrict__ vtb, const float* __restrict__ pos,
    short* __restrict__ outb) {
  // XCD swizzle: 768 % 8 == 0, 96 consecutive logical blocks per XCD
  const int bid = blockIdx.x;
  const int lb = (bid & 7) * 96 + (bid >> 3);
  const int qblk = lb & 7;
  const int bhid = lb >> 3;
  const int h = bhid % 12, b = bhid / 12;

  const int tid = threadIdx.x, lane = tid & 63, w = tid >> 6;
  const int c = lane & 15, g = lane >> 4;
  const size_t bh = (size_t)(b * 12 + h);
  const short* Q = qb + bh * SEQ * 64;
  const short* K = kb + bh * SEQ * 64;
  const short* VT = vtb + bh * 64 * SEQ;
  const float* Ph = pos + (size_t)h * SEQ * SEQ;
  const int q0w = qblk * 128 + w * 16;

  __shared__ short kls[3 * 4096];
  __shared__ short vls[3 * 4096];

  // Q as B-operand: col = q = c, k-dim = d; Q pre-scaled by QSCALE.
  bf16x8 qf0 = *(const bf16x8*)(Q + (size_t)(q0w + c) * 64 + g * 8);
  bf16x8 qf1 = *(const bf16x8*)(Q + (size_t)(q0w + c) * 64 + 32 + g * 8);

  const float* pbase = Ph + (size_t)(q0w + c) * SEQ + g * 4;

  f32x4 o[4];   // O^T accum: d = t2*16 + g*4 + j, q = c
#pragma unroll
  for (int t2 = 0; t2 < 4; ++t2) o[t2] = (f32x4){0.f, 0.f, 0.f, 0.f};
  float lsum = 0.f;          // per-lane partial; cross-lane reduced at end
  f32x4 pc[4], pn[4];

  // 8-wave STAGE: each thread 1 K-load + 1 V-load; wave w covers rows 8w..8w+7
  auto STAGE = [&](short* kb_, short* vb_, int kv0) {
    int row = w * 8 + (lane >> 3);
    int ul = (lane & 7) ^ (row & 7);
    gload_lds16(K + (size_t)(kv0 + row) * 64 + ul * 8, kb_ + w * 512);
    gload_lds16(VT + (size_t)row * SEQ + kv0 + ul * 8, vb_ + w * 512);
  };

  short* kbuf0 = kls;        short* vbuf0 = vls;
  short* kbuf1 = kls + 4096; short* vbuf1 = vls + 4096;
  short* kbuf2 = kls + 8192; short* vbuf2 = vls + 8192;

  // prologue: stage(0)[2], stage(1)[2], pos(0)[4]; newest 6 allowed in flight
  STAGE(kbuf0, vbuf0, 0);
  STAGE(kbuf1, vbuf1, 64);
#pragma unroll
  for (int t = 0; t < 4; ++t) pc[t] = *(const float4v*)(pbase + t * 16);
  asm volatile("s_waitcnt vmcnt(6)" ::: "memory");   // stage(0) landed
  __builtin_amdgcn_sched_barrier(0);
  __builtin_amdgcn_s_barrier();

  for (int ti = 0; ti < 16; ++ti) {
    const int kv0 = ti * 64;
    // top-of-tile issues: pos(ti+1)[4], stage(ti+2)[2]
    if (ti < 15) {
#pragma unroll
      for (int t = 0; t < 4; ++t)
        pn[t] = *(const float4v*)(pbase + (ti + 1) * 64 + t * 16);
    }
    if (ti < 14) STAGE(kbuf2, vbuf2, kv0 + 128);

    const short* kc = kbuf0;
    const short* vc = vbuf0;

    // QK^T swapped: A = K (rows = kv), B = Q (cols = q).
    f32x4 s[4];
    __builtin_amdgcn_s_setprio(1);
#pragma unroll
    for (int t = 0; t < 4; ++t) {
      int row = t * 16 + c;
      int sw = (row & 7) << 4;
      bf16x8 kf0 = *(const bf16x8*)((const char*)kc + ((row * 128 + g * 16) ^ sw));
      bf16x8 kf1 = *(const bf16x8*)((const char*)kc + ((row * 128 + 64 + g * 16) ^ sw));
      f32x4 z = (f32x4){0.f, 0.f, 0.f, 0.f};
      z = __builtin_amdgcn_mfma_f32_16x16x32_bf16(kf0, qf0, z, 0, 0, 0);
      s[t] = __builtin_amdgcn_mfma_f32_16x16x32_bf16(kf1, qf1, z, 0, 0, 0);
    }
    __builtin_amdgcn_s_setprio(0);

    // P = exp2(qk + pos*QSCALE) directly — no max subtraction needed
#pragma unroll
    for (int t = 0; t < 4; ++t)
#pragma unroll
      for (int j = 0; j < 4; ++j) {
        float p = exp2f(fmaf(pc[t][j], QSCALE, s[t][j]));
        s[t][j] = p;
        lsum += p;
      }

    // pack P^T to bf16 pairs
    unsigned pk00 = cvtpk(s[0][0], s[0][1]), pk01 = cvtpk(s[0][2], s[0][3]);
    unsigned pk10 = cvtpk(s[1][0], s[1][1]), pk11 = cvtpk(s[1][2], s[1][3]);
    unsigned pk20 = cvtpk(s[2][0], s[2][1]), pk21 = cvtpk(s[2][2], s[2][3]);
    unsigned pk30 = cvtpk(s[3][0], s[3][1]), pk31 = cvtpk(s[3][2], s[3][3]);

    // redistribute to PV B-frags: lane needs kv = m*32 + g*8 + i (i=0..7)
    int src0 = ((g * 2) & 3) * 16 + c;
    int src1 = src0 + 16;
    int hi = g >> 1;
    union { bf16x8 v; unsigned u[4]; } pb0, pb1;
    {
      unsigned a0 = (unsigned)__shfl((int)pk00, src0), b0 = (unsigned)__shfl((int)pk10, src0);
      unsigned a1 = (unsigned)__shfl((int)pk01, src0), b1 = (unsigned)__shfl((int)pk11, src0);
      unsigned a2 = (unsigned)__shfl((int)pk00, src1), b2 = (unsigned)__shfl((int)pk10, src1);
      unsigned a3 = (unsigned)__shfl((int)pk01, src1), b3 = (unsigned)__shfl((int)pk11, src1);
      pb0.u[0] = hi ? b0 : a0; pb0.u[1] = hi ? b1 : a1;
      pb0.u[2] = hi ? b2 : a2; pb0.u[3] = hi ? b3 : a3;
    }
    {
      unsigned a0 = (unsigned)__shfl((int)pk20, src0), b0 = (unsigned)__shfl((int)pk30, src0);
      unsigned a1 = (unsigned)__shfl((int)pk21, src0), b1 = (unsigned)__shfl((int)pk31, src0);
      unsigned a2 = (unsigned)__shfl((int)pk20, src1), b2 = (unsigned)__shfl((int)pk30, src1);
      unsigned a3 = (unsigned)__shfl((int)pk21, src1), b3 = (unsigned)__shfl((int)pk31, src1);
      pb1.u[0] = hi ? b0 : a0; pb1.u[1] = hi ? b1 : a1;
      pb1.u[2] = hi ? b2 : a2; pb1.u[3] = hi ? b3 : a3;
    }

    // PV: O^T += V^T(rows=d) x P^T(cols=q)
    __builtin_amdgcn_s_setprio(1);
#pragma unroll
    for (int t2 = 0; t2 < 4; ++t2) {
      int rv = t2 * 16 + c;
      int swv = (rv & 7) << 4;
      bf16x8 vf0 = *(const bf16x8*)((const char*)vc + ((rv * 128 + g * 16) ^ swv));
      bf16x8 vf1 = *(const bf16x8*)((const char*)vc + ((rv * 128 + 64 + g * 16) ^ swv));
      o[t2] = __builtin_amdgcn_mfma_f32_16x16x32_bf16(vf0, pb0.v, o[t2], 0, 0, 0);
      o[t2] = __builtin_amdgcn_mfma_f32_16x16x32_bf16(vf1, pb1.v, o[t2], 0, 0, 0);
    }
    __builtin_amdgcn_s_setprio(0);

#pragma unroll
    for (int t = 0; t < 4; ++t) pc[t] = pn[t];

    // rotate buffers: next tile reads buf1; freshly staged tile went to buf2
    short* tk = kbuf0; kbuf0 = kbuf1; kbuf1 = kbuf2; kbuf2 = tk;
    short* tv = vbuf0; vbuf0 = vbuf1; vbuf1 = vbuf2; vbuf2 = tv;

    // prove own stage(ti+1) landed BEFORE publishing barrier.
    // newer-than-stage(ti+1): pos(ti+1)[4] + stage(ti+2)[2]
    if (ti < 14)       asm volatile("s_waitcnt vmcnt(6)" ::: "memory");
    else if (ti == 14) asm volatile("s_waitcnt vmcnt(4)" ::: "memory");
    __builtin_amdgcn_sched_barrier(0);
    if (ti < 15) __builtin_amdgcn_s_barrier();
  }

  // deferred cross-lane lsum reduction (q-column group {c, c+16, c+32, c+48})
  lsum += __shfl_xor(lsum, 16);
  lsum += __shfl_xor(lsum, 32);
  float inv = 1.0f / lsum;
  size_t obase = (size_t)(b * SEQ + q0w + c) * 768 + h * 64;
#pragma unroll
  for (int t2 = 0; t2 < 4; ++t2) {
    short4v ov;
#pragma unroll
    for (int j = 0; j < 4; ++j) ov[j] = (short)f2bf(o[t2][j] * inv);
    *(short4v*)(outb + obase + t2 * 16 + g * 4) = ov;
  }
}

extern "C" void kernel_launch(void* const* d_in, const int* in_sizes, int n_in,
                              void* d_out, int out_size, void* d_ws, size_t ws_size,
                              hipStream_t stream) {
  const float* x      = (const float*)d_in[0];
  const float* pos    = (const float*)d_in[1];
  const float* W_qkv  = (const float*)d_in[2];
  const float* b_qkv  = (const float*)d_in[3];
  const float* W_proj = (const float*)d_in[4];
  const float* b_proj = (const float*)d_in[5];
  float* out = (float*)d_out;

  char* ws = (char*)d_ws;
  short* A       = (short*)(ws);                  // 12,582,912 (consumed by gemm<1>)
  short* attnbuf = (short*)(ws);                  // alias of A (written after)
  short* Bt      = (short*)(ws + 12582912);       //  3,538,944
  short* wpt     = (short*)(ws + 16121856);       //  1,179,648
  short* qbuf    = (short*)(ws + 17301504);       // 12,582,912
  short* kbuf    = (short*)(ws + 29884416);       // 12,582,912
  short* vtbuf   = (short*)(ws + 42467328);       // 12,582,912
  // total: 55,050,240 bytes

  prep_x_kernel<<<6144, 256, 0, stream>>>(x, A);
  prep_w_kernel<<<dim3(12, 36), 256, 0, stream>>>(W_qkv, Bt);
  prep_wp_kernel<<<dim3(12, 12), 256, 0, stream>>>(W_proj, wpt);
  gemm_kernel<1><<<dim3(18, 64), 256, 0, stream>>>(A, Bt, b_qkv,
                                                   qbuf, kbuf, vtbuf, nullptr);
  attn_kernel<<<768, 512, 0, stream>>>(qbuf, kbuf, vtbuf, pos, attnbuf);
  gemm_kernel<2><<<dim3(6, 64), 256, 0, stream>>>(attnbuf, wpt, b_proj,
                                                  nullptr, nullptr, nullptr, out);
}

// Round 7
// 173.302 us; speedup vs baseline: 1.5231x; 1.0880x over previous
//
#include <hip/hip_runtime.h>

#define SEQ   1024
#define HEADS 12
#define CDIM  768
#define BATCH 8

// 0.125 * log2(e): folds the 1/sqrt(64) score scale and the exp->exp2 change
#define QSCALE 0.18033688011112042f

typedef __attribute__((ext_vector_type(8))) short bf16x8;
typedef __attribute__((ext_vector_type(4))) float f32x4;
typedef __attribute__((ext_vector_type(16))) float f32x16;
typedef __attribute__((ext_vector_type(4))) float float4v;
typedef __attribute__((ext_vector_type(4))) short short4v;

__device__ __forceinline__ void gload_lds16(const void* g, void* l) {
  __builtin_amdgcn_global_load_lds(
      (const __attribute__((address_space(1))) unsigned int*)g,
      (__attribute__((address_space(3))) unsigned int*)l, 16, 0, 0);
}

__device__ __forceinline__ unsigned short f2bf(float f) {
  union { float f; unsigned u; } v; v.f = f;
  unsigned r = v.u + 0x7fff + ((v.u >> 16) & 1);
  return (unsigned short)(r >> 16);
}

// pack two f32 -> u32 of 2x bf16 (lo = a, hi = b); no builtin on gfx950
__device__ __forceinline__ unsigned cvtpk(float a, float b) {
  unsigned r;
  asm("v_cvt_pk_bf16_f32 %0, %1, %2" : "=v"(r) : "v"(a), "v"(b));
  return r;
}

// x [8192,768] f32 -> A [8192,768] bf16
__global__ __launch_bounds__(256) void prep_x_kernel(const float* __restrict__ x,
                                                     short* __restrict__ A) {
  int i = blockIdx.x * 256 + threadIdx.x;
  int r = i / 192;
  int c4 = (i % 192) * 4;
  float4v xv = *(const float4v*)(x + (size_t)r * 768 + c4);
  short4v hi;
#pragma unroll
  for (int j = 0; j < 4; ++j) hi[j] = (short)f2bf(xv[j]);
  *(short4v*)(A + (size_t)r * 768 + c4) = hi;
}

// W_qkv [768,2304] f32 -> Bt [2304,768] bf16 transposed
__global__ __launch_bounds__(256) void prep_w_kernel(const float* __restrict__ W,
                                                     short* __restrict__ Bt) {
  __shared__ float tile[64][65];
  int k0 = blockIdx.x * 64;
  int n0 = blockIdx.y * 64;
  int t = threadIdx.x;
#pragma unroll
  for (int it = 0; it < 16; ++it) {
    int r = it * 4 + (t >> 6);
    int c = t & 63;
    tile[r][c] = W[(size_t)(k0 + r) * 2304 + n0 + c];
  }
  __syncthreads();
#pragma unroll
  for (int it = 0; it < 16; ++it) {
    int nr = it * 4 + (t >> 6);
    int kc = t & 63;
    Bt[(size_t)(n0 + nr) * 768 + k0 + kc] = (short)f2bf(tile[kc][nr]);
  }
}

// W_proj [768,768] f32 -> Wpt [768,768] bf16 transposed
__global__ __launch_bounds__(256) void prep_wp_kernel(const float* __restrict__ W,
                                                      short* __restrict__ Bt) {
  __shared__ float tile[64][65];
  int k0 = blockIdx.x * 64;
  int n0 = blockIdx.y * 64;
  int t = threadIdx.x;
#pragma unroll
  for (int it = 0; it < 16; ++it) {
    int r = it * 4 + (t >> 6);
    int c = t & 63;
    tile[r][c] = W[(size_t)(k0 + r) * 768 + n0 + c];
  }
  __syncthreads();
#pragma unroll
  for (int it = 0; it < 16; ++it) {
    int nr = it * 4 + (t >> 6);
    int kc = t & 63;
    Bt[(size_t)(n0 + nr) * 768 + k0 + kc] = (short)f2bf(tile[kc][nr]);
  }
}

// Shared 128x128-tile GEMM, BK=64, K=768, 4 waves, 16x16x32 bf16 MFMA.
template <int MODE>
__global__ __launch_bounds__(256) void gemm_kernel(
    const short* __restrict__ A, const short* __restrict__ Bt,
    const float* __restrict__ bias,
    short* __restrict__ outQ, short* __restrict__ outK, short* __restrict__ outVT,
    float* __restrict__ outF) {
  const int n0 = blockIdx.x * 128;
  const int m0 = blockIdx.y * 128;
  __shared__ short Als[128 * 64];
  __shared__ short Bls[128 * 64];
  const int tid = threadIdx.x;
  const int lane = tid & 63;
  const int w = tid >> 6;
  const int wr = (w >> 1) * 64;
  const int wc = (w & 1) * 64;
  f32x4 acc[4][4];
#pragma unroll
  for (int mi = 0; mi < 4; ++mi)
#pragma unroll
    for (int ni = 0; ni < 4; ++ni) acc[mi][ni] = (f32x4){0.f, 0.f, 0.f, 0.f};

  for (int k0 = 0; k0 < 768; k0 += 64) {
#pragma unroll
    for (int it = 0; it < 4; ++it) {
      int rbase = it * 32 + w * 8;
      int row = rbase + (lane >> 3);
      int ul = (lane & 7) ^ (row & 7);
      gload_lds16(A + (size_t)(m0 + row) * 768 + k0 + ul * 8, Als + rbase * 64);
      gload_lds16(Bt + (size_t)(n0 + row) * 768 + k0 + ul * 8, Bls + rbase * 64);
    }
    __syncthreads();
#pragma unroll
    for (int kk = 0; kk < 2; ++kk) {
      bf16x8 af[4], bfv[4];
#pragma unroll
      for (int mi = 0; mi < 4; ++mi) {
        int row = wr + mi * 16 + (lane & 15);
        int off = (row * 128 + kk * 64 + (lane >> 4) * 16) ^ ((row & 7) << 4);
        af[mi] = *(const bf16x8*)((const char*)Als + off);
      }
#pragma unroll
      for (int ni = 0; ni < 4; ++ni) {
        int row = wc + ni * 16 + (lane & 15);
        int off = (row * 128 + kk * 64 + (lane >> 4) * 16) ^ ((row & 7) << 4);
        bfv[ni] = *(const bf16x8*)((const char*)Bls + off);
      }
#pragma unroll
      for (int mi = 0; mi < 4; ++mi)
#pragma unroll
        for (int ni = 0; ni < 4; ++ni)
          acc[mi][ni] = __builtin_amdgcn_mfma_f32_16x16x32_bf16(
              af[mi], bfv[ni], acc[mi][ni], 0, 0, 0);
    }
    __syncthreads();
  }
#pragma unroll
  for (int mi = 0; mi < 4; ++mi)
#pragma unroll
    for (int ni = 0; ni < 4; ++ni)
#pragma unroll
      for (int j = 0; j < 4; ++j) {
        int row = m0 + wr + mi * 16 + ((lane >> 4) << 2) + j;
        int col = n0 + wc + ni * 16 + (lane & 15);
        float v = acc[mi][ni][j] + bias[col];
        if (MODE == 1) {
          int three = col / 768;
          int rem = col - three * 768;
          int h = rem >> 6, d = rem & 63;
          int b = row >> 10, n = row & 1023;
          size_t bh = (size_t)(b * 12 + h);
          if (three == 0)      outQ[(bh * 1024 + n) * 64 + d] = (short)f2bf(v * QSCALE);
          else if (three == 1) outK[(bh * 1024 + n) * 64 + d] = (short)f2bf(v);
          else                 outVT[(bh * 64 + d) * 1024 + n] = (short)f2bf(v);
        } else {
          outF[(size_t)row * 768 + col] = v;
        }
      }
}

// build one PV B-frag (4 u32 = 8 bf16, k = kv) from packed P pairs:
// permlane32_swap(x=pk[m][p], y=pk[m+1][p]) -> x' = frag reg (own|swap),
// y' = frag reg (swap|own) for the two lane halves. 4 swaps per 32-kv block.
#define MKFRAG(B, pA, pB, pC, pD)                                    \
  { unsigned x0 = (pA), y0 = (pC), x1 = (pB), y1 = (pD);             \
    asm("v_permlane32_swap_b32 %0, %1" : "+v"(x0), "+v"(y0));        \
    asm("v_permlane32_swap_b32 %0, %1" : "+v"(x1), "+v"(y1));        \
    B.u[0] = x0; B.u[1] = x1; B.u[2] = y0; B.u[3] = y1; }

// Flash attention, 32x32x16 MFMA, swapped QK^T, fixed-shift softmax,
// permlane32_swap P-redistribute (no bpermute), distance-2 KV pipeline,
// distance-0 early pos loads, h-major XCD swizzle.
// grid: 768 blocks x 256 threads; 4 waves x 32 q-rows (QBLK=128).
__global__ __launch_bounds__(256, 3) void attn_kernel(
    const short* __restrict__ qb, const short* __restrict__ kb,
    const short* __restrict__ vtb, const float* __restrict__ pos,
    short* __restrict__ outb) {
  // h-major XCD swizzle: XCD gets 96 consecutive lb; lb -> (qblk, h*8+b)
  // => the 8 same-(h,qblk) diff-b blocks (identical pos rows) share one XCD L2.
  const int bid = blockIdx.x;
  const int lb = (bid & 7) * 96 + (bid >> 3);
  const int qblk = lb & 7;
  const int hb = lb >> 3;            // 0..95 = h*8 + b
  const int h = hb >> 3, b = hb & 7;

  const int tid = threadIdx.x, lane = tid & 63, w = tid >> 6;
  const int c5 = lane & 31, g1 = lane >> 5;
  const size_t bh = (size_t)(b * 12 + h);
  const short* Q = qb + bh * SEQ * 64;
  const short* K = kb + bh * SEQ * 64;
  const short* VT = vtb + bh * 64 * SEQ;
  const float* Ph = pos + (size_t)h * SEQ * SEQ;
  const int q0w = qblk * 128 + w * 32;

  __shared__ short kls[3 * 4096];
  __shared__ short vls[3 * 4096];

  // Q as B-operand of 32x32x16: B[k=16kd+8g1+i][col q=c5]; Q pre-scaled.
  bf16x8 qf[4];
#pragma unroll
  for (int kd = 0; kd < 4; ++kd)
    qf[kd] = *(const bf16x8*)(Q + (size_t)(q0w + c5) * 64 + kd * 16 + g1 * 8);

  const float* pbase = Ph + (size_t)(q0w + c5) * SEQ + g1 * 4;

  f32x16 o0, o1;    // O^T: rows d = (r&3)+8*(r>>2)+4g1 (+32 for o1), col q=c5
#pragma unroll
  for (int i = 0; i < 16; ++i) { o0[i] = 0.f; o1[i] = 0.f; }
  float lsum = 0.f;

  // 4-wave STAGE: 2 K + 2 V gload_lds per thread (wave w: rows 8w..8w+7, +32)
  auto STAGE = [&](short* kb_, short* vb_, int kv0) {
    int r0 = w * 8 + (lane >> 3);
    int u0 = (lane & 7) ^ (r0 & 7);
    gload_lds16(K + (size_t)(kv0 + r0) * 64 + u0 * 8, kb_ + w * 512);
    gload_lds16(K + (size_t)(kv0 + 32 + r0) * 64 + u0 * 8, kb_ + 2048 + w * 512);
    gload_lds16(VT + (size_t)r0 * SEQ + kv0 + u0 * 8, vb_ + w * 512);
    gload_lds16(VT + (size_t)(32 + r0) * SEQ + kv0 + u0 * 8, vb_ + 2048 + w * 512);
  };

  short* kbuf0 = kls;        short* vbuf0 = vls;
  short* kbuf1 = kls + 4096; short* vbuf1 = vls + 4096;
  short* kbuf2 = kls + 8192; short* vbuf2 = vls + 8192;

  STAGE(kbuf0, vbuf0, 0);
  STAGE(kbuf1, vbuf1, 64);
  asm volatile("s_waitcnt vmcnt(4)" ::: "memory");   // stage(0) landed
  __builtin_amdgcn_sched_barrier(0);
  __builtin_amdgcn_s_barrier();

  for (int ti = 0; ti < 16; ++ti) {
    const int kv0 = ti * 64;

    // distance-0 pos loads, issued FIRST (consumed after QK^T)
    float4v pv0[4], pv1[4];
#pragma unroll
    for (int m = 0; m < 4; ++m) {
      pv0[m] = *(const float4v*)(pbase + kv0 + m * 8);
      pv1[m] = *(const float4v*)(pbase + kv0 + 32 + m * 8);
    }
    asm volatile("" ::: "memory");   // pin pos-issue before STAGE
    if (ti < 14) STAGE(kbuf2, vbuf2, kv0 + 128);

    const short* kc = kbuf0;
    const short* vc = vbuf0;

    // QK^T swapped: A = K rows kv (2 blocks of 32), B = Q cols q.
    f32x16 p0, p1;
#pragma unroll
    for (int i = 0; i < 16; ++i) { p0[i] = 0.f; p1[i] = 0.f; }
    __builtin_amdgcn_s_setprio(1);
#pragma unroll
    for (int kd = 0; kd < 4; ++kd) {
      int off0 = (c5 * 128 + kd * 32 + g1 * 16) ^ ((c5 & 7) << 4);
      int off1 = ((32 + c5) * 128 + kd * 32 + g1 * 16) ^ ((c5 & 7) << 4);
      bf16x8 kf0 = *(const bf16x8*)((const char*)kc + off0);
      bf16x8 kf1 = *(const bf16x8*)((const char*)kc + off1);
      p0 = __builtin_amdgcn_mfma_f32_32x32x16_bf16(kf0, qf[kd], p0, 0, 0, 0);
      p1 = __builtin_amdgcn_mfma_f32_32x32x16_bf16(kf1, qf[kd], p1, 0, 0, 0);
    }
    __builtin_amdgcn_s_setprio(0);

    // P = exp2(qk + pos*QSCALE); reg r: kv = (r&3)+8*(r>>2)+4g1 (+32 for p1)
#pragma unroll
    for (int r = 0; r < 16; ++r) {
      float a = exp2f(fmaf(pv0[r >> 2][r & 3], QSCALE, p0[r]));
      float bq = exp2f(fmaf(pv1[r >> 2][r & 3], QSCALE, p1[r]));
      p0[r] = a; p1[r] = bq;
      lsum += a + bq;
    }

    // pack pairs along j: pk[2m+p] = (kv=8m+4g1+2p, +1)
    unsigned pk0[8], pk1[8];
#pragma unroll
    for (int m = 0; m < 4; ++m) {
      pk0[2 * m]     = cvtpk(p0[4 * m],     p0[4 * m + 1]);
      pk0[2 * m + 1] = cvtpk(p0[4 * m + 2], p0[4 * m + 3]);
      pk1[2 * m]     = cvtpk(p1[4 * m],     p1[4 * m + 1]);
      pk1[2 * m + 1] = cvtpk(p1[4 * m + 2], p1[4 * m + 3]);
    }

    // PV B-frags: step s covers kv 16s..16s+15; k = 8g1+i
    union bb { bf16x8 v; unsigned u[4]; } B0, B1, B2, B3;
    MKFRAG(B0, pk0[0], pk0[1], pk0[2], pk0[3]);   // s=0 (m=0,1)
    MKFRAG(B1, pk0[4], pk0[5], pk0[6], pk0[7]);   // s=1 (m=2,3)
    MKFRAG(B2, pk1[0], pk1[1], pk1[2], pk1[3]);   // s=2
    MKFRAG(B3, pk1[4], pk1[5], pk1[6], pk1[7]);   // s=3

    // PV: O^T += V^T (A, rows d) x P^T (B, cols q)
    __builtin_amdgcn_s_setprio(1);
#define PVSTEP(Bv, s)                                                        \
    { int o0f = (c5 * 128 + (s) * 32 + g1 * 16) ^ ((c5 & 7) << 4);           \
      int o1f = ((32 + c5) * 128 + (s) * 32 + g1 * 16) ^ ((c5 & 7) << 4);    \
      bf16x8 vf0 = *(const bf16x8*)((const char*)vc + o0f);                  \
      bf16x8 vf1 = *(const bf16x8*)((const char*)vc + o1f);                  \
      o0 = __builtin_amdgcn_mfma_f32_32x32x16_bf16(vf0, Bv.v, o0, 0, 0, 0);  \
      o1 = __builtin_amdgcn_mfma_f32_32x32x16_bf16(vf1, Bv.v, o1, 0, 0, 0); }
    PVSTEP(B0, 0); PVSTEP(B1, 1); PVSTEP(B2, 2); PVSTEP(B3, 3);
#undef PVSTEP
    __builtin_amdgcn_s_setprio(0);

    // rotate buffers
    short* tk = kbuf0; kbuf0 = kbuf1; kbuf1 = kbuf2; kbuf2 = tk;
    short* tv = vbuf0; vbuf0 = vbuf1; vbuf1 = vbuf2; vbuf2 = tv;

    // pos consumed above -> only stage(ti+2)[4] may remain in flight.
    if (ti < 15) {
      if (ti < 14) asm volatile("s_waitcnt vmcnt(4)" ::: "memory");
      else         asm volatile("s_waitcnt vmcnt(0)" ::: "memory");
      __builtin_amdgcn_sched_barrier(0);
      __builtin_amdgcn_s_barrier();
    }
  }

  // lane and lane^32 hold complementary kv rows of the same q-column
  lsum += __shfl_xor(lsum, 32);
  float inv = 1.0f / lsum;
  size_t obase = (size_t)(b * SEQ + q0w + c5) * 768 + h * 64 + g1 * 4;
#pragma unroll
  for (int m = 0; m < 4; ++m) {
    short4v ov0, ov1;
#pragma unroll
    for (int j = 0; j < 4; ++j) {
      ov0[j] = (short)f2bf(o0[4 * m + j] * inv);
      ov1[j] = (short)f2bf(o1[4 * m + j] * inv);
    }
    *(short4v*)(outb + obase + m * 8) = ov0;
    *(short4v*)(outb + obase + 32 + m * 8) = ov1;
  }
}

extern "C" void kernel_launch(void* const* d_in, const int* in_sizes, int n_in,
                              void* d_out, int out_size, void* d_ws, size_t ws_size,
                              hipStream_t stream) {
  const float* x      = (const float*)d_in[0];
  const float* pos    = (const float*)d_in[1];
  const float* W_qkv  = (const float*)d_in[2];
  const float* b_qkv  = (const float*)d_in[3];
  const float* W_proj = (const float*)d_in[4];
  const float* b_proj = (const float*)d_in[5];
  float* out = (float*)d_out;

  char* ws = (char*)d_ws;
  short* A       = (short*)(ws);                  // 12,582,912 (consumed by gemm<1>)
  short* attnbuf = (short*)(ws);                  // alias of A (written after)
  short* Bt      = (short*)(ws + 12582912);       //  3,538,944
  short* wpt     = (short*)(ws + 16121856);       //  1,179,648
  short* qbuf    = (short*)(ws + 17301504);       // 12,582,912
  short* kbuf    = (short*)(ws + 29884416);       // 12,582,912
  short* vtbuf   = (short*)(ws + 42467328);       // 12,582,912
  // total: 55,050,240 bytes

  prep_x_kernel<<<6144, 256, 0, stream>>>(x, A);
  prep_w_kernel<<<dim3(12, 36), 256, 0, stream>>>(W_qkv, Bt);
  prep_wp_kernel<<<dim3(12, 12), 256, 0, stream>>>(W_proj, wpt);
  gemm_kernel<1><<<dim3(18, 64), 256, 0, stream>>>(A, Bt, b_qkv,
                                                   qbuf, kbuf, vtbuf, nullptr);
  attn_kernel<<<768, 256, 0, stream>>>(qbuf, kbuf, vtbuf, pos, attnbuf);
  gemm_kernel<2><<<dim3(6, 64), 256, 0, stream>>>(attnbuf, wpt, b_proj,
                                                  nullptr, nullptr, nullptr, out);
}

// Round 8
// 168.415 us; speedup vs baseline: 1.5673x; 1.0290x over previous
//
#include <hip/hip_runtime.h>

#define SEQ   1024
#define HEADS 12
#define CDIM  768
#define BATCH 8

// 0.125 * log2(e): folds the 1/sqrt(64) score scale and the exp->exp2 change
#define QSCALE 0.18033688011112042f

typedef __attribute__((ext_vector_type(8))) short bf16x8;
typedef __attribute__((ext_vector_type(4))) float f32x4;
typedef __attribute__((ext_vector_type(16))) float f32x16;
typedef __attribute__((ext_vector_type(4))) float float4v;
typedef __attribute__((ext_vector_type(4))) short short4v;

__device__ __forceinline__ void gload_lds16(const void* g, void* l) {
  __builtin_amdgcn_global_load_lds(
      (const __attribute__((address_space(1))) unsigned int*)g,
      (__attribute__((address_space(3))) unsigned int*)l, 16, 0, 0);
}

__device__ __forceinline__ unsigned short f2bf(float f) {
  union { float f; unsigned u; } v; v.f = f;
  unsigned r = v.u + 0x7fff + ((v.u >> 16) & 1);
  return (unsigned short)(r >> 16);
}

// pack two f32 -> u32 of 2x bf16 (lo = a, hi = b); no builtin on gfx950
__device__ __forceinline__ unsigned cvtpk(float a, float b) {
  unsigned r;
  asm("v_cvt_pk_bf16_f32 %0, %1, %2" : "=v"(r) : "v"(a), "v"(b));
  return r;
}

// select bf16 half of a packed u32 as f32 (odd -> high half, even -> low)
__device__ __forceinline__ float bfsel(unsigned u, int odd) {
  union { unsigned u; float f; } v;
  v.u = odd ? (u & 0xffff0000u) : (u << 16);
  return v.f;
}

// x [8192,768] f32 -> A [8192,768] bf16
__global__ __launch_bounds__(256) void prep_x_kernel(const float* __restrict__ x,
                                                     short* __restrict__ A) {
  int i = blockIdx.x * 256 + threadIdx.x;
  int r = i / 192;
  int c4 = (i % 192) * 4;
  float4v xv = *(const float4v*)(x + (size_t)r * 768 + c4);
  short4v hi;
#pragma unroll
  for (int j = 0; j < 4; ++j) hi[j] = (short)f2bf(xv[j]);
  *(short4v*)(A + (size_t)r * 768 + c4) = hi;
}

// W_qkv [768,2304] f32 -> Bt [2304,768] bf16 transposed
__global__ __launch_bounds__(256) void prep_w_kernel(const float* __restrict__ W,
                                                     short* __restrict__ Bt) {
  __shared__ float tile[64][65];
  int k0 = blockIdx.x * 64;
  int n0 = blockIdx.y * 64;
  int t = threadIdx.x;
#pragma unroll
  for (int it = 0; it < 16; ++it) {
    int r = it * 4 + (t >> 6);
    int c = t & 63;
    tile[r][c] = W[(size_t)(k0 + r) * 2304 + n0 + c];
  }
  __syncthreads();
#pragma unroll
  for (int it = 0; it < 16; ++it) {
    int nr = it * 4 + (t >> 6);
    int kc = t & 63;
    Bt[(size_t)(n0 + nr) * 768 + k0 + kc] = (short)f2bf(tile[kc][nr]);
  }
}

// W_proj [768,768] f32 -> Wpt [768,768] bf16 transposed
__global__ __launch_bounds__(256) void prep_wp_kernel(const float* __restrict__ W,
                                                      short* __restrict__ Bt) {
  __shared__ float tile[64][65];
  int k0 = blockIdx.x * 64;
  int n0 = blockIdx.y * 64;
  int t = threadIdx.x;
#pragma unroll
  for (int it = 0; it < 16; ++it) {
    int r = it * 4 + (t >> 6);
    int c = t & 63;
    tile[r][c] = W[(size_t)(k0 + r) * 768 + n0 + c];
  }
  __syncthreads();
#pragma unroll
  for (int it = 0; it < 16; ++it) {
    int nr = it * 4 + (t >> 6);
    int kc = t & 63;
    Bt[(size_t)(n0 + nr) * 768 + k0 + kc] = (short)f2bf(tile[kc][nr]);
  }
}

// pos [12,1024,1024] f32 -> posb bf16 (QSCALE-folded), pre-swizzled to the
// attn kernel's per-lane register order:
//   index = ((((((h*8+qblk)*16 + ti)*4 + w)*2 + i0)*2 + jh)*64 + lane)*8 + jl
//   value = pos[h][qblk*128 + w*32 + (lane&31)]
//              [ti*64 + i0*32 + 4*(lane>>5) + 16*jh + (jl&3) + 8*(jl>>2)] * QSCALE
// Each posb element is consumed by exactly one lane -> pure stream, and the
// attn-side loads are 16B/lane wave-dense (1KB per instruction).
__global__ __launch_bounds__(256) void prep_pos_kernel(const float* __restrict__ P,
                                                       short* __restrict__ PB) {
  int t = blockIdx.x * 256 + threadIdx.x;   // 12<<17 = 1,572,864 threads
  int lane = t & 63;
  int jh   = (t >> 6) & 1;
  int i0   = (t >> 7) & 1;
  int w    = (t >> 8) & 3;
  int ti   = (t >> 10) & 15;
  int qblk = (t >> 14) & 7;
  int h    = t >> 17;
  int c5 = lane & 31, g1 = lane >> 5;
  int q = qblk * 128 + w * 32 + c5;
  const float* src = P + ((size_t)h * SEQ + q) * SEQ
                     + ti * 64 + i0 * 32 + 4 * g1 + 16 * jh;
  float4v v0 = *(const float4v*)(src);       // jl = 0..3  (kv +0..3)
  float4v v1 = *(const float4v*)(src + 8);   // jl = 4..7  (kv +8..11)
  union { short s[8]; bf16x8 v; } o;
#pragma unroll
  for (int p = 0; p < 4; ++p) {
    o.s[p]     = (short)f2bf(v0[p] * QSCALE);
    o.s[4 + p] = (short)f2bf(v1[p] * QSCALE);
  }
  *(bf16x8*)(PB + (size_t)t * 8) = o.v;
}

// Shared 128x128-tile GEMM, BK=64, K=768, 4 waves, 16x16x32 bf16 MFMA.
template <int MODE>
__global__ __launch_bounds__(256) void gemm_kernel(
    const short* __restrict__ A, const short* __restrict__ Bt,
    const float* __restrict__ bias,
    short* __restrict__ outQ, short* __restrict__ outK, short* __restrict__ outVT,
    float* __restrict__ outF) {
  const int n0 = blockIdx.x * 128;
  const int m0 = blockIdx.y * 128;
  __shared__ short Als[128 * 64];
  __shared__ short Bls[128 * 64];
  const int tid = threadIdx.x;
  const int lane = tid & 63;
  const int w = tid >> 6;
  const int wr = (w >> 1) * 64;
  const int wc = (w & 1) * 64;
  f32x4 acc[4][4];
#pragma unroll
  for (int mi = 0; mi < 4; ++mi)
#pragma unroll
    for (int ni = 0; ni < 4; ++ni) acc[mi][ni] = (f32x4){0.f, 0.f, 0.f, 0.f};

  for (int k0 = 0; k0 < 768; k0 += 64) {
#pragma unroll
    for (int it = 0; it < 4; ++it) {
      int rbase = it * 32 + w * 8;
      int row = rbase + (lane >> 3);
      int ul = (lane & 7) ^ (row & 7);
      gload_lds16(A + (size_t)(m0 + row) * 768 + k0 + ul * 8, Als + rbase * 64);
      gload_lds16(Bt + (size_t)(n0 + row) * 768 + k0 + ul * 8, Bls + rbase * 64);
    }
    __syncthreads();
#pragma unroll
    for (int kk = 0; kk < 2; ++kk) {
      bf16x8 af[4], bfv[4];
#pragma unroll
      for (int mi = 0; mi < 4; ++mi) {
        int row = wr + mi * 16 + (lane & 15);
        int off = (row * 128 + kk * 64 + (lane >> 4) * 16) ^ ((row & 7) << 4);
        af[mi] = *(const bf16x8*)((const char*)Als + off);
      }
#pragma unroll
      for (int ni = 0; ni < 4; ++ni) {
        int row = wc + ni * 16 + (lane & 15);
        int off = (row * 128 + kk * 64 + (lane >> 4) * 16) ^ ((row & 7) << 4);
        bfv[ni] = *(const bf16x8*)((const char*)Bls + off);
      }
#pragma unroll
      for (int mi = 0; mi < 4; ++mi)
#pragma unroll
        for (int ni = 0; ni < 4; ++ni)
          acc[mi][ni] = __builtin_amdgcn_mfma_f32_16x16x32_bf16(
              af[mi], bfv[ni], acc[mi][ni], 0, 0, 0);
    }
    __syncthreads();
  }
  if (MODE == 1) {
    // block-uniform third: 128 | 768, so col/768 is constant per block
    const int three = n0 / 768;
    const int nb = n0 - three * 768;
#pragma unroll
    for (int mi = 0; mi < 4; ++mi)
#pragma unroll
      for (int ni = 0; ni < 4; ++ni)
#pragma unroll
        for (int j = 0; j < 4; ++j) {
          int row = m0 + wr + mi * 16 + ((lane >> 4) << 2) + j;
          int col = n0 + wc + ni * 16 + (lane & 15);
          float v = acc[mi][ni][j] + bias[col];
          int rem = nb + wc + ni * 16 + (lane & 15);
          int hh = rem >> 6, d = rem & 63;
          int b = row >> 10, n = row & 1023;
          size_t bh = (size_t)(b * 12 + hh);
          if (three == 0)      outQ[(bh * 1024 + n) * 64 + d] = (short)f2bf(v * QSCALE);
          else if (three == 1) outK[(bh * 1024 + n) * 64 + d] = (short)f2bf(v);
          else                 outVT[(bh * 64 + d) * 1024 + n] = (short)f2bf(v);
        }
  } else {
#pragma unroll
    for (int mi = 0; mi < 4; ++mi)
#pragma unroll
      for (int ni = 0; ni < 4; ++ni)
#pragma unroll
        for (int j = 0; j < 4; ++j) {
          int row = m0 + wr + mi * 16 + ((lane >> 4) << 2) + j;
          int col = n0 + wc + ni * 16 + (lane & 15);
          outF[(size_t)row * 768 + col] = acc[mi][ni][j] + bias[col];
        }
  }
}

// build one PV B-frag (4 u32 = 8 bf16, k = kv) from packed P pairs:
// permlane32_swap(x=pk[m][p], y=pk[m+1][p]) -> x' = frag reg (own|swap),
// y' = frag reg (swap|own) for the two lane halves. 4 swaps per 32-kv block.
#define MKFRAG(B, pA, pB, pC, pD)                                    \
  { unsigned x0 = (pA), y0 = (pC), x1 = (pB), y1 = (pD);             \
    asm("v_permlane32_swap_b32 %0, %1" : "+v"(x0), "+v"(y0));        \
    asm("v_permlane32_swap_b32 %0, %1" : "+v"(x1), "+v"(y1));        \
    B.u[0] = x0; B.u[1] = x1; B.u[2] = y0; B.u[3] = y1; }

// Flash attention, 32x32x16 MFMA, swapped QK^T, fixed-shift softmax,
// permlane32_swap P-redistribute, distance-2 KV pipeline, coalesced
// pre-swizzled bf16 pos (QSCALE folded), h-major XCD swizzle.
// grid: 768 blocks x 256 threads; 4 waves x 32 q-rows (QBLK=128).
__global__ __launch_bounds__(256, 3) void attn_kernel(
    const short* __restrict__ qb, const short* __restrict__ kb,
    const short* __restrict__ vtb, const short* __restrict__ posb,
    short* __restrict__ outb) {
  // h-major XCD swizzle: the 8 same-(h,qblk) diff-b blocks share one XCD L2.
  const int bid = blockIdx.x;
  const int lb = (bid & 7) * 96 + (bid >> 3);
  const int qblk = lb & 7;
  const int hb = lb >> 3;            // 0..95 = h*8 + b
  const int h = hb >> 3, b = hb & 7;

  const int tid = threadIdx.x, lane = tid & 63, w = tid >> 6;
  const int c5 = lane & 31, g1 = lane >> 5;
  const size_t bh = (size_t)(b * 12 + h);
  const short* Q = qb + bh * SEQ * 64;
  const short* K = kb + bh * SEQ * 64;
  const short* VT = vtb + bh * 64 * SEQ;
  const int q0w = qblk * 128 + w * 32;

  // per-(block,wave,lane) base into pre-swizzled pos (shorts)
  const short* pwb = posb + (size_t)h * 1048576 + (size_t)qblk * 131072
                     + w * 2048 + lane * 8;

  __shared__ short kls[3 * 4096];
  __shared__ short vls[3 * 4096];

  // Q as B-operand of 32x32x16: B[k=16kd+8g1+i][col q=c5]; Q pre-scaled.
  bf16x8 qf[4];
#pragma unroll
  for (int kd = 0; kd < 4; ++kd)
    qf[kd] = *(const bf16x8*)(Q + (size_t)(q0w + c5) * 64 + kd * 16 + g1 * 8);

  f32x16 o0, o1;    // O^T: rows d = (r&3)+8*(r>>2)+4g1 (+32 for o1), col q=c5
#pragma unroll
  for (int i = 0; i < 16; ++i) { o0[i] = 0.f; o1[i] = 0.f; }
  float lsum = 0.f;

  // 4-wave STAGE: 2 K + 2 V gload_lds per thread (wave w: rows 8w..8w+7, +32)
  auto STAGE = [&](short* kb_, short* vb_, int kv0) {
    int r0 = w * 8 + (lane >> 3);
    int u0 = (lane & 7) ^ (r0 & 7);
    gload_lds16(K + (size_t)(kv0 + r0) * 64 + u0 * 8, kb_ + w * 512);
    gload_lds16(K + (size_t)(kv0 + 32 + r0) * 64 + u0 * 8, kb_ + 2048 + w * 512);
    gload_lds16(VT + (size_t)r0 * SEQ + kv0 + u0 * 8, vb_ + w * 512);
    gload_lds16(VT + (size_t)(32 + r0) * SEQ + kv0 + u0 * 8, vb_ + 2048 + w * 512);
  };

  short* kbuf0 = kls;        short* vbuf0 = vls;
  short* kbuf1 = kls + 4096; short* vbuf1 = vls + 4096;
  short* kbuf2 = kls + 8192; short* vbuf2 = vls + 8192;

  STAGE(kbuf0, vbuf0, 0);
  STAGE(kbuf1, vbuf1, 64);
  asm volatile("s_waitcnt vmcnt(4)" ::: "memory");   // stage(0) landed
  __builtin_amdgcn_sched_barrier(0);
  __builtin_amdgcn_s_barrier();

  for (int ti = 0; ti < 16; ++ti) {
    const int kv0 = ti * 64;

    // coalesced pos loads (4 x 16B, wave-dense), consumed in softmax
    union { bf16x8 v; unsigned u[4]; } ua0, ua1, ub0, ub1;
    ua0.v = *(const bf16x8*)(pwb + ti * 8192);          // i0=0, jh=0 -> r=0..7
    ua1.v = *(const bf16x8*)(pwb + ti * 8192 + 512);    // i0=0, jh=1 -> r=8..15
    ub0.v = *(const bf16x8*)(pwb + ti * 8192 + 1024);   // i0=1, jh=0
    ub1.v = *(const bf16x8*)(pwb + ti * 8192 + 1536);   // i0=1, jh=1
    asm volatile("" ::: "memory");   // pin pos-issue before STAGE
    if (ti < 14) STAGE(kbuf2, vbuf2, kv0 + 128);

    const short* kc = kbuf0;
    const short* vc = vbuf0;

    // QK^T swapped: A = K rows kv (2 blocks of 32), B = Q cols q.
    f32x16 p0, p1;
#pragma unroll
    for (int i = 0; i < 16; ++i) { p0[i] = 0.f; p1[i] = 0.f; }
    __builtin_amdgcn_s_setprio(1);
#pragma unroll
    for (int kd = 0; kd < 4; ++kd) {
      int off0 = (c5 * 128 + kd * 32 + g1 * 16) ^ ((c5 & 7) << 4);
      int off1 = ((32 + c5) * 128 + kd * 32 + g1 * 16) ^ ((c5 & 7) << 4);
      bf16x8 kf0 = *(const bf16x8*)((const char*)kc + off0);
      bf16x8 kf1 = *(const bf16x8*)((const char*)kc + off1);
      p0 = __builtin_amdgcn_mfma_f32_32x32x16_bf16(kf0, qf[kd], p0, 0, 0, 0);
      p1 = __builtin_amdgcn_mfma_f32_32x32x16_bf16(kf1, qf[kd], p1, 0, 0, 0);
    }
    __builtin_amdgcn_s_setprio(0);

    // P = exp2(qk + pos); reg r: kv = (r&3)+8*(r>>2)+4g1 (+32 for p1)
#pragma unroll
    for (int r = 0; r < 16; ++r) {
      unsigned wa = (r < 8) ? ua0.u[(r >> 1) & 3] : ua1.u[(r >> 1) & 3];
      unsigned wb = (r < 8) ? ub0.u[(r >> 1) & 3] : ub1.u[(r >> 1) & 3];
      float a = exp2f(p0[r] + bfsel(wa, r & 1));
      float bq = exp2f(p1[r] + bfsel(wb, r & 1));
      p0[r] = a; p1[r] = bq;
      lsum += a + bq;
    }

    // pack pairs along j: pk[2m+p] = (kv=8m+4g1+2p, +1)
    unsigned pk0[8], pk1[8];
#pragma unroll
    for (int m = 0; m < 4; ++m) {
      pk0[2 * m]     = cvtpk(p0[4 * m],     p0[4 * m + 1]);
      pk0[2 * m + 1] = cvtpk(p0[4 * m + 2], p0[4 * m + 3]);
      pk1[2 * m]     = cvtpk(p1[4 * m],     p1[4 * m + 1]);
      pk1[2 * m + 1] = cvtpk(p1[4 * m + 2], p1[4 * m + 3]);
    }

    // PV B-frags: step s covers kv 16s..16s+15; k = 8g1+i
    union bb { bf16x8 v; unsigned u[4]; } B0, B1, B2, B3;
    MKFRAG(B0, pk0[0], pk0[1], pk0[2], pk0[3]);   // s=0
    MKFRAG(B1, pk0[4], pk0[5], pk0[6], pk0[7]);   // s=1
    MKFRAG(B2, pk1[0], pk1[1], pk1[2], pk1[3]);   // s=2
    MKFRAG(B3, pk1[4], pk1[5], pk1[6], pk1[7]);   // s=3

    // PV: O^T += V^T (A, rows d) x P^T (B, cols q)
    __builtin_amdgcn_s_setprio(1);
#define PVSTEP(Bv, s)                                                        \
    { int o0f = (c5 * 128 + (s) * 32 + g1 * 16) ^ ((c5 & 7) << 4);           \
      int o1f = ((32 + c5) * 128 + (s) * 32 + g1 * 16) ^ ((c5 & 7) << 4);    \
      bf16x8 vf0 = *(const bf16x8*)((const char*)vc + o0f);                  \
      bf16x8 vf1 = *(const bf16x8*)((const char*)vc + o1f);                  \
      o0 = __builtin_amdgcn_mfma_f32_32x32x16_bf16(vf0, Bv.v, o0, 0, 0, 0);  \
      o1 = __builtin_amdgcn_mfma_f32_32x32x16_bf16(vf1, Bv.v, o1, 0, 0, 0); }
    PVSTEP(B0, 0); PVSTEP(B1, 1); PVSTEP(B2, 2); PVSTEP(B3, 3);
#undef PVSTEP
    __builtin_amdgcn_s_setprio(0);

    // rotate buffers
    short* tk = kbuf0; kbuf0 = kbuf1; kbuf1 = kbuf2; kbuf2 = tk;
    short* tv = vbuf0; vbuf0 = vbuf1; vbuf1 = vbuf2; vbuf2 = tv;

    // pos consumed above -> only stage(ti+2)[4] may remain in flight.
    if (ti < 15) {
      if (ti < 14) asm volatile("s_waitcnt vmcnt(4)" ::: "memory");
      else         asm volatile("s_waitcnt vmcnt(0)" ::: "memory");
      __builtin_amdgcn_sched_barrier(0);
      __builtin_amdgcn_s_barrier();
    }
  }

  // lane and lane^32 hold complementary kv rows of the same q-column
  lsum += __shfl_xor(lsum, 32);
  float inv = 1.0f / lsum;
  size_t obase = (size_t)(b * SEQ + q0w + c5) * 768 + h * 64 + g1 * 4;
#pragma unroll
  for (int m = 0; m < 4; ++m) {
    short4v ov0, ov1;
#pragma unroll
    for (int j = 0; j < 4; ++j) {
      ov0[j] = (short)f2bf(o0[4 * m + j] * inv);
      ov1[j] = (short)f2bf(o1[4 * m + j] * inv);
    }
    *(short4v*)(outb + obase + m * 8) = ov0;
    *(short4v*)(outb + obase + 32 + m * 8) = ov1;
  }
}

extern "C" void kernel_launch(void* const* d_in, const int* in_sizes, int n_in,
                              void* d_out, int out_size, void* d_ws, size_t ws_size,
                              hipStream_t stream) {
  const float* x      = (const float*)d_in[0];
  const float* pos    = (const float*)d_in[1];
  const float* W_qkv  = (const float*)d_in[2];
  const float* b_qkv  = (const float*)d_in[3];
  const float* W_proj = (const float*)d_in[4];
  const float* b_proj = (const float*)d_in[5];
  float* out = (float*)d_out;

  char* ws = (char*)d_ws;
  short* A       = (short*)(ws);                  // 12,582,912 (consumed by gemm<1>)
  short* attnbuf = (short*)(ws);                  // alias of A (written after)
  short* Bt      = (short*)(ws + 12582912);       //  3,538,944
  short* wpt     = (short*)(ws + 16121856);       //  1,179,648
  short* qbuf    = (short*)(ws + 17301504);       // 12,582,912
  short* kbuf    = (short*)(ws + 29884416);       // 12,582,912
  short* vtbuf   = (short*)(ws + 42467328);       // 12,582,912
  short* posb    = (short*)(ws + 55050240);       // 25,165,824
  // total: 80,216,064 bytes

  prep_x_kernel<<<6144, 256, 0, stream>>>(x, A);
  prep_w_kernel<<<dim3(12, 36), 256, 0, stream>>>(W_qkv, Bt);
  prep_wp_kernel<<<dim3(12, 12), 256, 0, stream>>>(W_proj, wpt);
  prep_pos_kernel<<<6144, 256, 0, stream>>>(pos, posb);
  gemm_kernel<1><<<dim3(18, 64), 256, 0, stream>>>(A, Bt, b_qkv,
                                                   qbuf, kbuf, vtbuf, nullptr);
  attn_kernel<<<768, 256, 0, stream>>>(qbuf, kbuf, vtbuf, posb, attnbuf);
  gemm_kernel<2><<<dim3(6, 64), 256, 0, stream>>>(attnbuf, wpt, b_proj,
                                                  nullptr, nullptr, nullptr, out);
}

// Round 9
// 159.663 us; speedup vs baseline: 1.6532x; 1.0548x over previous
//
#include <hip/hip_runtime.h>

#define SEQ   1024
#define HEADS 12
#define CDIM  768
#define BATCH 8

// 0.125 * log2(e): folds the 1/sqrt(64) score scale and the exp->exp2 change
#define QSCALE 0.18033688011112042f

typedef __attribute__((ext_vector_type(8))) short bf16x8;
typedef __attribute__((ext_vector_type(4))) float f32x4;
typedef __attribute__((ext_vector_type(16))) float f32x16;
typedef __attribute__((ext_vector_type(4))) float float4v;
typedef __attribute__((ext_vector_type(4))) short short4v;

__device__ __forceinline__ void gload_lds16(const void* g, void* l) {
  __builtin_amdgcn_global_load_lds(
      (const __attribute__((address_space(1))) unsigned int*)g,
      (__attribute__((address_space(3))) unsigned int*)l, 16, 0, 0);
}

__device__ __forceinline__ unsigned short f2bf(float f) {
  union { float f; unsigned u; } v; v.f = f;
  unsigned r = v.u + 0x7fff + ((v.u >> 16) & 1);
  return (unsigned short)(r >> 16);
}

// pack two f32 -> u32 of 2x bf16 (lo = a, hi = b); no builtin on gfx950
__device__ __forceinline__ unsigned cvtpk(float a, float b) {
  unsigned r;
  asm("v_cvt_pk_bf16_f32 %0, %1, %2" : "=v"(r) : "v"(a), "v"(b));
  return r;
}

// select bf16 half of a packed u32 as f32 (odd -> high half, even -> low)
__device__ __forceinline__ float bfsel(unsigned u, int odd) {
  union { unsigned u; float f; } v;
  v.u = odd ? (u & 0xffff0000u) : (u << 16);
  return v.f;
}

// x [8192,768] f32 -> A [8192,768] bf16
__global__ __launch_bounds__(256) void prep_x_kernel(const float* __restrict__ x,
                                                     short* __restrict__ A) {
  int i = blockIdx.x * 256 + threadIdx.x;
  int r = i / 192;
  int c4 = (i % 192) * 4;
  float4v xv = *(const float4v*)(x + (size_t)r * 768 + c4);
  short4v hi;
#pragma unroll
  for (int j = 0; j < 4; ++j) hi[j] = (short)f2bf(xv[j]);
  *(short4v*)(A + (size_t)r * 768 + c4) = hi;
}

// W_qkv [768,2304] f32 -> Bt [2304,768] bf16 transposed
__global__ __launch_bounds__(256) void prep_w_kernel(const float* __restrict__ W,
                                                     short* __restrict__ Bt) {
  __shared__ float tile[64][65];
  int k0 = blockIdx.x * 64;
  int n0 = blockIdx.y * 64;
  int t = threadIdx.x;
#pragma unroll
  for (int it = 0; it < 16; ++it) {
    int r = it * 4 + (t >> 6);
    int c = t & 63;
    tile[r][c] = W[(size_t)(k0 + r) * 2304 + n0 + c];
  }
  __syncthreads();
#pragma unroll
  for (int it = 0; it < 16; ++it) {
    int nr = it * 4 + (t >> 6);
    int kc = t & 63;
    Bt[(size_t)(n0 + nr) * 768 + k0 + kc] = (short)f2bf(tile[kc][nr]);
  }
}

// W_proj [768,768] f32 -> Wpt [768,768] bf16 transposed
__global__ __launch_bounds__(256) void prep_wp_kernel(const float* __restrict__ W,
                                                      short* __restrict__ Bt) {
  __shared__ float tile[64][65];
  int k0 = blockIdx.x * 64;
  int n0 = blockIdx.y * 64;
  int t = threadIdx.x;
#pragma unroll
  for (int it = 0; it < 16; ++it) {
    int r = it * 4 + (t >> 6);
    int c = t & 63;
    tile[r][c] = W[(size_t)(k0 + r) * 768 + n0 + c];
  }
  __syncthreads();
#pragma unroll
  for (int it = 0; it < 16; ++it) {
    int nr = it * 4 + (t >> 6);
    int kc = t & 63;
    Bt[(size_t)(n0 + nr) * 768 + k0 + kc] = (short)f2bf(tile[kc][nr]);
  }
}

// pos [12,1024,1024] f32 -> posb bf16 (QSCALE-folded), pre-swizzled to the
// attn kernel's per-lane register order (each element consumed exactly once).
__global__ __launch_bounds__(256) void prep_pos_kernel(const float* __restrict__ P,
                                                       short* __restrict__ PB) {
  int t = blockIdx.x * 256 + threadIdx.x;   // 12<<17 = 1,572,864 threads
  int lane = t & 63;
  int jh   = (t >> 6) & 1;
  int i0   = (t >> 7) & 1;
  int w    = (t >> 8) & 3;
  int ti   = (t >> 10) & 15;
  int qblk = (t >> 14) & 7;
  int h    = t >> 17;
  int c5 = lane & 31, g1 = lane >> 5;
  int q = qblk * 128 + w * 32 + c5;
  const float* src = P + ((size_t)h * SEQ + q) * SEQ
                     + ti * 64 + i0 * 32 + 4 * g1 + 16 * jh;
  float4v v0 = *(const float4v*)(src);       // jl = 0..3  (kv +0..3)
  float4v v1 = *(const float4v*)(src + 8);   // jl = 4..7  (kv +8..11)
  union { short s[8]; bf16x8 v; } o;
#pragma unroll
  for (int p = 0; p < 4; ++p) {
    o.s[p]     = (short)f2bf(v0[p] * QSCALE);
    o.s[4 + p] = (short)f2bf(v1[p] * QSCALE);
  }
  *(bf16x8*)(PB + (size_t)t * 8) = o.v;
}

// Shared 128x128-tile GEMM, BK=64, K=768, 4 waves, 16x16x32 bf16 MFMA.
// 2-phase issue-early pipeline (T3-minimum): STAGE(t+1) issued BEFORE
// compute(t); one vmcnt(0)+s_barrier per K-step (no drain-before-compute).
template <int MODE>
__global__ __launch_bounds__(256) void gemm_kernel(
    const short* __restrict__ A, const short* __restrict__ Bt,
    const float* __restrict__ bias,
    short* __restrict__ outQ, short* __restrict__ outK, short* __restrict__ outVT,
    float* __restrict__ outF) {
  const int n0 = blockIdx.x * 128;
  const int m0 = blockIdx.y * 128;
  __shared__ short Als[2][128 * 64];
  __shared__ short Bls[2][128 * 64];
  const int tid = threadIdx.x;
  const int lane = tid & 63;
  const int w = tid >> 6;
  const int wr = (w >> 1) * 64;
  const int wc = (w & 1) * 64;
  f32x4 acc[4][4];
#pragma unroll
  for (int mi = 0; mi < 4; ++mi)
#pragma unroll
    for (int ni = 0; ni < 4; ++ni) acc[mi][ni] = (f32x4){0.f, 0.f, 0.f, 0.f};

  auto STAGE = [&](int buf, int k0) {
#pragma unroll
    for (int it = 0; it < 4; ++it) {
      int rbase = it * 32 + w * 8;
      int row = rbase + (lane >> 3);
      int ul = (lane & 7) ^ (row & 7);
      gload_lds16(A + (size_t)(m0 + row) * 768 + k0 + ul * 8, Als[buf] + rbase * 64);
      gload_lds16(Bt + (size_t)(n0 + row) * 768 + k0 + ul * 8, Bls[buf] + rbase * 64);
    }
  };

  STAGE(0, 0);
  asm volatile("s_waitcnt vmcnt(0)" ::: "memory");
  __builtin_amdgcn_sched_barrier(0);
  __builtin_amdgcn_s_barrier();

  for (int t = 0; t < 12; ++t) {
    if (t < 11) STAGE((t + 1) & 1, (t + 1) * 64);   // loads fly during compute
    const short* Ab = Als[t & 1];
    const short* Bb = Bls[t & 1];
#pragma unroll
    for (int kk = 0; kk < 2; ++kk) {
      bf16x8 af[4], bfv[4];
#pragma unroll
      for (int mi = 0; mi < 4; ++mi) {
        int row = wr + mi * 16 + (lane & 15);
        int off = (row * 128 + kk * 64 + (lane >> 4) * 16) ^ ((row & 7) << 4);
        af[mi] = *(const bf16x8*)((const char*)Ab + off);
      }
#pragma unroll
      for (int ni = 0; ni < 4; ++ni) {
        int row = wc + ni * 16 + (lane & 15);
        int off = (row * 128 + kk * 64 + (lane >> 4) * 16) ^ ((row & 7) << 4);
        bfv[ni] = *(const bf16x8*)((const char*)Bb + off);
      }
#pragma unroll
      for (int mi = 0; mi < 4; ++mi)
#pragma unroll
        for (int ni = 0; ni < 4; ++ni)
          acc[mi][ni] = __builtin_amdgcn_mfma_f32_16x16x32_bf16(
              af[mi], bfv[ni], acc[mi][ni], 0, 0, 0);
    }
    if (t < 11) {
      // own stage(t+1) proven landed before the publishing barrier
      asm volatile("s_waitcnt vmcnt(0)" ::: "memory");
      __builtin_amdgcn_sched_barrier(0);
      __builtin_amdgcn_s_barrier();
    }
  }

  if (MODE == 1) {
    // block-uniform third: 128 | 768, so col/768 is constant per block
    const int three = n0 / 768;
    const int nb = n0 - three * 768;
#pragma unroll
    for (int mi = 0; mi < 4; ++mi)
#pragma unroll
      for (int ni = 0; ni < 4; ++ni)
#pragma unroll
        for (int j = 0; j < 4; ++j) {
          int row = m0 + wr + mi * 16 + ((lane >> 4) << 2) + j;
          int col = n0 + wc + ni * 16 + (lane & 15);
          float v = acc[mi][ni][j] + bias[col];
          int rem = nb + wc + ni * 16 + (lane & 15);
          int hh = rem >> 6, d = rem & 63;
          int b = row >> 10, n = row & 1023;
          size_t bh = (size_t)(b * 12 + hh);
          if (three == 0)      outQ[(bh * 1024 + n) * 64 + d] = (short)f2bf(v * QSCALE);
          else if (three == 1) outK[(bh * 1024 + n) * 64 + d] = (short)f2bf(v);
          else                 outVT[(bh * 64 + d) * 1024 + n] = (short)f2bf(v);
        }
  } else {
#pragma unroll
    for (int mi = 0; mi < 4; ++mi)
#pragma unroll
      for (int ni = 0; ni < 4; ++ni)
#pragma unroll
        for (int j = 0; j < 4; ++j) {
          int row = m0 + wr + mi * 16 + ((lane >> 4) << 2) + j;
          int col = n0 + wc + ni * 16 + (lane & 15);
          outF[(size_t)row * 768 + col] = acc[mi][ni][j] + bias[col];
        }
  }
}

// build one PV B-frag (4 u32 = 8 bf16, k = kv) from packed P pairs:
// permlane32_swap(x=pk[m][p], y=pk[m+1][p]) -> x' = frag reg (own|swap),
// y' = frag reg (swap|own) for the two lane halves. 4 swaps per 32-kv block.
#define MKFRAG(B, pA, pB, pC, pD)                                    \
  { unsigned x0 = (pA), y0 = (pC), x1 = (pB), y1 = (pD);             \
    asm("v_permlane32_swap_b32 %0, %1" : "+v"(x0), "+v"(y0));        \
    asm("v_permlane32_swap_b32 %0, %1" : "+v"(x1), "+v"(y1));        \
    B.u[0] = x0; B.u[1] = x1; B.u[2] = y0; B.u[3] = y1; }

// Flash attention, 32x32x16 MFMA, swapped QK^T, fixed-shift softmax,
// permlane32_swap P-redistribute, distance-2 KV pipeline, coalesced
// pre-swizzled bf16 pos (QSCALE folded), h-major XCD swizzle.
// grid: 768 blocks x 256 threads; 4 waves x 32 q-rows (QBLK=128).
__global__ __launch_bounds__(256, 3) void attn_kernel(
    const short* __restrict__ qb, const short* __restrict__ kb,
    const short* __restrict__ vtb, const short* __restrict__ posb,
    short* __restrict__ outb) {
  // h-major XCD swizzle: the 8 same-(h,qblk) diff-b blocks share one XCD L2.
  const int bid = blockIdx.x;
  const int lb = (bid & 7) * 96 + (bid >> 3);
  const int qblk = lb & 7;
  const int hb = lb >> 3;            // 0..95 = h*8 + b
  const int h = hb >> 3, b = hb & 7;

  const int tid = threadIdx.x, lane = tid & 63, w = tid >> 6;
  const int c5 = lane & 31, g1 = lane >> 5;
  const size_t bh = (size_t)(b * 12 + h);
  const short* Q = qb + bh * SEQ * 64;
  const short* K = kb + bh * SEQ * 64;
  const short* VT = vtb + bh * 64 * SEQ;
  const int q0w = qblk * 128 + w * 32;

  // per-(block,wave,lane) base into pre-swizzled pos (shorts)
  const short* pwb = posb + (size_t)h * 1048576 + (size_t)qblk * 131072
                     + w * 2048 + lane * 8;

  __shared__ short kls[3 * 4096];
  __shared__ short vls[3 * 4096];

  // Q as B-operand of 32x32x16: B[k=16kd+8g1+i][col q=c5]; Q pre-scaled.
  bf16x8 qf[4];
#pragma unroll
  for (int kd = 0; kd < 4; ++kd)
    qf[kd] = *(const bf16x8*)(Q + (size_t)(q0w + c5) * 64 + kd * 16 + g1 * 8);

  f32x16 o0, o1;    // O^T: rows d = (r&3)+8*(r>>2)+4g1 (+32 for o1), col q=c5
#pragma unroll
  for (int i = 0; i < 16; ++i) { o0[i] = 0.f; o1[i] = 0.f; }
  float lsum = 0.f;

  // 4-wave STAGE: 2 K + 2 V gload_lds per thread (wave w: rows 8w..8w+7, +32)
  auto STAGE = [&](short* kb_, short* vb_, int kv0) {
    int r0 = w * 8 + (lane >> 3);
    int u0 = (lane & 7) ^ (r0 & 7);
    gload_lds16(K + (size_t)(kv0 + r0) * 64 + u0 * 8, kb_ + w * 512);
    gload_lds16(K + (size_t)(kv0 + 32 + r0) * 64 + u0 * 8, kb_ + 2048 + w * 512);
    gload_lds16(VT + (size_t)r0 * SEQ + kv0 + u0 * 8, vb_ + w * 512);
    gload_lds16(VT + (size_t)(32 + r0) * SEQ + kv0 + u0 * 8, vb_ + 2048 + w * 512);
  };

  short* kbuf0 = kls;        short* vbuf0 = vls;
  short* kbuf1 = kls + 4096; short* vbuf1 = vls + 4096;
  short* kbuf2 = kls + 8192; short* vbuf2 = vls + 8192;

  STAGE(kbuf0, vbuf0, 0);
  STAGE(kbuf1, vbuf1, 64);
  asm volatile("s_waitcnt vmcnt(4)" ::: "memory");   // stage(0) landed
  __builtin_amdgcn_sched_barrier(0);
  __builtin_amdgcn_s_barrier();

  for (int ti = 0; ti < 16; ++ti) {
    const int kv0 = ti * 64;

    // coalesced pos loads (4 x 16B, wave-dense), consumed in softmax
    union { bf16x8 v; unsigned u[4]; } ua0, ua1, ub0, ub1;
    ua0.v = *(const bf16x8*)(pwb + ti * 8192);          // i0=0, jh=0 -> r=0..7
    ua1.v = *(const bf16x8*)(pwb + ti * 8192 + 512);    // i0=0, jh=1 -> r=8..15
    ub0.v = *(const bf16x8*)(pwb + ti * 8192 + 1024);   // i0=1, jh=0
    ub1.v = *(const bf16x8*)(pwb + ti * 8192 + 1536);   // i0=1, jh=1
    asm volatile("" ::: "memory");   // pin pos-issue before STAGE
    if (ti < 14) STAGE(kbuf2, vbuf2, kv0 + 128);

    const short* kc = kbuf0;
    const short* vc = vbuf0;

    // QK^T swapped: A = K rows kv (2 blocks of 32), B = Q cols q.
    f32x16 p0, p1;
#pragma unroll
    for (int i = 0; i < 16; ++i) { p0[i] = 0.f; p1[i] = 0.f; }
    __builtin_amdgcn_s_setprio(1);
#pragma unroll
    for (int kd = 0; kd < 4; ++kd) {
      int off0 = (c5 * 128 + kd * 32 + g1 * 16) ^ ((c5 & 7) << 4);
      int off1 = ((32 + c5) * 128 + kd * 32 + g1 * 16) ^ ((c5 & 7) << 4);
      bf16x8 kf0 = *(const bf16x8*)((const char*)kc + off0);
      bf16x8 kf1 = *(const bf16x8*)((const char*)kc + off1);
      p0 = __builtin_amdgcn_mfma_f32_32x32x16_bf16(kf0, qf[kd], p0, 0, 0, 0);
      p1 = __builtin_amdgcn_mfma_f32_32x32x16_bf16(kf1, qf[kd], p1, 0, 0, 0);
    }
    __builtin_amdgcn_s_setprio(0);

    // P = exp2(qk + pos); reg r: kv = (r&3)+8*(r>>2)+4g1 (+32 for p1)
#pragma unroll
    for (int r = 0; r < 16; ++r) {
      unsigned wa = (r < 8) ? ua0.u[(r >> 1) & 3] : ua1.u[(r >> 1) & 3];
      unsigned wb = (r < 8) ? ub0.u[(r >> 1) & 3] : ub1.u[(r >> 1) & 3];
      float a = exp2f(p0[r] + bfsel(wa, r & 1));
      float bq = exp2f(p1[r] + bfsel(wb, r & 1));
      p0[r] = a; p1[r] = bq;
      lsum += a + bq;
    }

    // pack pairs along j: pk[2m+p] = (kv=8m+4g1+2p, +1)
    unsigned pk0[8], pk1[8];
#pragma unroll
    for (int m = 0; m < 4; ++m) {
      pk0[2 * m]     = cvtpk(p0[4 * m],     p0[4 * m + 1]);
      pk0[2 * m + 1] = cvtpk(p0[4 * m + 2], p0[4 * m + 3]);
      pk1[2 * m]     = cvtpk(p1[4 * m],     p1[4 * m + 1]);
      pk1[2 * m + 1] = cvtpk(p1[4 * m + 2], p1[4 * m + 3]);
    }

    // PV B-frags: step s covers kv 16s..16s+15; k = 8g1+i
    union bb { bf16x8 v; unsigned u[4]; } B0, B1, B2, B3;
    MKFRAG(B0, pk0[0], pk0[1], pk0[2], pk0[3]);   // s=0
    MKFRAG(B1, pk0[4], pk0[5], pk0[6], pk0[7]);   // s=1
    MKFRAG(B2, pk1[0], pk1[1], pk1[2], pk1[3]);   // s=2
    MKFRAG(B3, pk1[4], pk1[5], pk1[6], pk1[7]);   // s=3

    // PV: O^T += V^T (A, rows d) x P^T (B, cols q)
    __builtin_amdgcn_s_setprio(1);
#define PVSTEP(Bv, s)                                                        \
    { int o0f = (c5 * 128 + (s) * 32 + g1 * 16) ^ ((c5 & 7) << 4);           \
      int o1f = ((32 + c5) * 128 + (s) * 32 + g1 * 16) ^ ((c5 & 7) << 4);    \
      bf16x8 vf0 = *(const bf16x8*)((const char*)vc + o0f);                  \
      bf16x8 vf1 = *(const bf16x8*)((const char*)vc + o1f);                  \
      o0 = __builtin_amdgcn_mfma_f32_32x32x16_bf16(vf0, Bv.v, o0, 0, 0, 0);  \
      o1 = __builtin_amdgcn_mfma_f32_32x32x16_bf16(vf1, Bv.v, o1, 0, 0, 0); }
    PVSTEP(B0, 0); PVSTEP(B1, 1); PVSTEP(B2, 2); PVSTEP(B3, 3);
#undef PVSTEP
    __builtin_amdgcn_s_setprio(0);

    // rotate buffers
    short* tk = kbuf0; kbuf0 = kbuf1; kbuf1 = kbuf2; kbuf2 = tk;
    short* tv = vbuf0; vbuf0 = vbuf1; vbuf1 = vbuf2; vbuf2 = tv;

    // pos consumed above -> only stage(ti+2)[4] may remain in flight.
    if (ti < 15) {
      if (ti < 14) asm volatile("s_waitcnt vmcnt(4)" ::: "memory");
      else         asm volatile("s_waitcnt vmcnt(0)" ::: "memory");
      __builtin_amdgcn_sched_barrier(0);
      __builtin_amdgcn_s_barrier();
    }
  }

  // lane and lane^32 hold complementary kv rows of the same q-column
  lsum += __shfl_xor(lsum, 32);
  float inv = 1.0f / lsum;
  size_t obase = (size_t)(b * SEQ + q0w + c5) * 768 + h * 64 + g1 * 4;
#pragma unroll
  for (int m = 0; m < 4; ++m) {
    short4v ov0, ov1;
#pragma unroll
    for (int j = 0; j < 4; ++j) {
      ov0[j] = (short)f2bf(o0[4 * m + j] * inv);
      ov1[j] = (short)f2bf(o1[4 * m + j] * inv);
    }
    *(short4v*)(outb + obase + m * 8) = ov0;
    *(short4v*)(outb + obase + 32 + m * 8) = ov1;
  }
}

extern "C" void kernel_launch(void* const* d_in, const int* in_sizes, int n_in,
                              void* d_out, int out_size, void* d_ws, size_t ws_size,
                              hipStream_t stream) {
  const float* x      = (const float*)d_in[0];
  const float* pos    = (const float*)d_in[1];
  const float* W_qkv  = (const float*)d_in[2];
  const float* b_qkv  = (const float*)d_in[3];
  const float* W_proj = (const float*)d_in[4];
  const float* b_proj = (const float*)d_in[5];
  float* out = (float*)d_out;

  char* ws = (char*)d_ws;
  short* A       = (short*)(ws);                  // 12,582,912 (consumed by gemm<1>)
  short* attnbuf = (short*)(ws);                  // alias of A (written after)
  short* Bt      = (short*)(ws + 12582912);       //  3,538,944
  short* wpt     = (short*)(ws + 16121856);       //  1,179,648
  short* qbuf    = (short*)(ws + 17301504);       // 12,582,912
  short* kbuf    = (short*)(ws + 29884416);       // 12,582,912
  short* vtbuf   = (short*)(ws + 42467328);       // 12,582,912
  short* posb    = (short*)(ws + 55050240);       // 25,165,824
  // total: 80,216,064 bytes

  prep_x_kernel<<<6144, 256, 0, stream>>>(x, A);
  prep_w_kernel<<<dim3(12, 36), 256, 0, stream>>>(W_qkv, Bt);
  prep_wp_kernel<<<dim3(12, 12), 256, 0, stream>>>(W_proj, wpt);
  prep_pos_kernel<<<6144, 256, 0, stream>>>(pos, posb);
  gemm_kernel<1><<<dim3(18, 64), 256, 0, stream>>>(A, Bt, b_qkv,
                                                   qbuf, kbuf, vtbuf, nullptr);
  attn_kernel<<<768, 256, 0, stream>>>(qbuf, kbuf, vtbuf, posb, attnbuf);
  gemm_kernel<2><<<dim3(6, 64), 256, 0, stream>>>(attnbuf, wpt, b_proj,
                                                  nullptr, nullptr, nullptr, out);
}

// Round 10
// 152.572 us; speedup vs baseline: 1.7300x; 1.0465x over previous
//
#include <hip/hip_runtime.h>

#define SEQ   1024
#define HEADS 12
#define CDIM  768
#define BATCH 8

// 0.125 * log2(e): folds the 1/sqrt(64) score scale and the exp->exp2 change
#define QSCALE 0.18033688011112042f

typedef __attribute__((ext_vector_type(8))) short bf16x8;
typedef __attribute__((ext_vector_type(4))) float f32x4;
typedef __attribute__((ext_vector_type(16))) float f32x16;
typedef __attribute__((ext_vector_type(4))) float float4v;
typedef __attribute__((ext_vector_type(4))) short short4v;

__device__ __forceinline__ void gload_lds16(const void* g, void* l) {
  __builtin_amdgcn_global_load_lds(
      (const __attribute__((address_space(1))) unsigned int*)g,
      (__attribute__((address_space(3))) unsigned int*)l, 16, 0, 0);
}

__device__ __forceinline__ unsigned short f2bf(float f) {
  union { float f; unsigned u; } v; v.f = f;
  unsigned r = v.u + 0x7fff + ((v.u >> 16) & 1);
  return (unsigned short)(r >> 16);
}

// pack two f32 -> u32 of 2x bf16 (lo = a, hi = b); no builtin on gfx950
__device__ __forceinline__ unsigned cvtpk(float a, float b) {
  unsigned r;
  asm("v_cvt_pk_bf16_f32 %0, %1, %2" : "=v"(r) : "v"(a), "v"(b));
  return r;
}

// select bf16 half of a packed u32 as f32 (odd -> high half, even -> low)
__device__ __forceinline__ float bfsel(unsigned u, int odd) {
  union { unsigned u; float f; } v;
  v.u = odd ? (u & 0xffff0000u) : (u << 16);
  return v.f;
}

// x [8192,768] f32 -> A [8192,768] bf16
__global__ __launch_bounds__(256) void prep_x_kernel(const float* __restrict__ x,
                                                     short* __restrict__ A) {
  int i = blockIdx.x * 256 + threadIdx.x;
  int r = i / 192;
  int c4 = (i % 192) * 4;
  float4v xv = *(const float4v*)(x + (size_t)r * 768 + c4);
  short4v hi;
#pragma unroll
  for (int j = 0; j < 4; ++j) hi[j] = (short)f2bf(xv[j]);
  *(short4v*)(A + (size_t)r * 768 + c4) = hi;
}

// W_qkv [768,2304] f32 -> Bt [2304,768] bf16 transposed
__global__ __launch_bounds__(256) void prep_w_kernel(const float* __restrict__ W,
                                                     short* __restrict__ Bt) {
  __shared__ float tile[64][65];
  int k0 = blockIdx.x * 64;
  int n0 = blockIdx.y * 64;
  int t = threadIdx.x;
#pragma unroll
  for (int it = 0; it < 16; ++it) {
    int r = it * 4 + (t >> 6);
    int c = t & 63;
    tile[r][c] = W[(size_t)(k0 + r) * 2304 + n0 + c];
  }
  __syncthreads();
#pragma unroll
  for (int it = 0; it < 16; ++it) {
    int nr = it * 4 + (t >> 6);
    int kc = t & 63;
    Bt[(size_t)(n0 + nr) * 768 + k0 + kc] = (short)f2bf(tile[kc][nr]);
  }
}

// W_proj [768,768] f32 -> Wpt [768,768] bf16 transposed
__global__ __launch_bounds__(256) void prep_wp_kernel(const float* __restrict__ W,
                                                      short* __restrict__ Bt) {
  __shared__ float tile[64][65];
  int k0 = blockIdx.x * 64;
  int n0 = blockIdx.y * 64;
  int t = threadIdx.x;
#pragma unroll
  for (int it = 0; it < 16; ++it) {
    int r = it * 4 + (t >> 6);
    int c = t & 63;
    tile[r][c] = W[(size_t)(k0 + r) * 768 + n0 + c];
  }
  __syncthreads();
#pragma unroll
  for (int it = 0; it < 16; ++it) {
    int nr = it * 4 + (t >> 6);
    int kc = t & 63;
    Bt[(size_t)(n0 + nr) * 768 + k0 + kc] = (short)f2bf(tile[kc][nr]);
  }
}

// pos [12,1024,1024] f32 -> posb bf16 (QSCALE-folded), pre-swizzled to the
// attn kernel's per-lane register order (each element consumed exactly once).
__global__ __launch_bounds__(256) void prep_pos_kernel(const float* __restrict__ P,
                                                       short* __restrict__ PB) {
  int t = blockIdx.x * 256 + threadIdx.x;   // 12<<17 = 1,572,864 threads
  int lane = t & 63;
  int jh   = (t >> 6) & 1;
  int i0   = (t >> 7) & 1;
  int w    = (t >> 8) & 3;
  int ti   = (t >> 10) & 15;
  int qblk = (t >> 14) & 7;
  int h    = t >> 17;
  int c5 = lane & 31, g1 = lane >> 5;
  int q = qblk * 128 + w * 32 + c5;
  const float* src = P + ((size_t)h * SEQ + q) * SEQ
                     + ti * 64 + i0 * 32 + 4 * g1 + 16 * jh;
  float4v v0 = *(const float4v*)(src);       // jl = 0..3  (kv +0..3)
  float4v v1 = *(const float4v*)(src + 8);   // jl = 4..7  (kv +8..11)
  union { short s[8]; bf16x8 v; } o;
#pragma unroll
  for (int p = 0; p < 4; ++p) {
    o.s[p]     = (short)f2bf(v0[p] * QSCALE);
    o.s[4 + p] = (short)f2bf(v1[p] * QSCALE);
  }
  *(bf16x8*)(PB + (size_t)t * 8) = o.v;
}

// Shared 128x128-tile GEMM, BK=64, K=768, 8 waves (2x4), 16x16x32 bf16 MFMA.
// 2-phase issue-early pipeline; 512 threads -> 16 waves/CU (4/SIMD) at
// 2 blocks/CU; XCD-chunked linear grid for L2 locality.
// MODE 1: qkv (N=2304, 18 n-blocks); MODE 2: proj (N=768, 6 n-blocks).
template <int MODE>
__global__ __launch_bounds__(512, 4) void gemm_kernel(
    const short* __restrict__ A, const short* __restrict__ Bt,
    const float* __restrict__ bias,
    short* __restrict__ outQ, short* __restrict__ outK, short* __restrict__ outVT,
    float* __restrict__ outF) {
  constexpr int NBLK = (MODE == 1) ? 18 : 6;     // n-blocks per m-row
  constexpr int CHUNK = (MODE == 1) ? 144 : 48;  // nwg/8 (both divisible)
  const int bid = blockIdx.x;
  const int lb = (bid & 7) * CHUNK + (bid >> 3); // XCD-chunked, bijective
  const int n0 = (lb % NBLK) * 128;
  const int m0 = (lb / NBLK) * 128;

  __shared__ short Als[2][128 * 64];
  __shared__ short Bls[2][128 * 64];
  const int tid = threadIdx.x;
  const int lane = tid & 63;
  const int w = tid >> 6;
  const int wr = (w & 1) * 64;       // 2 row-groups of 64
  const int wc = (w >> 1) * 32;      // 4 col-groups of 32
  f32x4 acc[4][2];
#pragma unroll
  for (int mi = 0; mi < 4; ++mi)
#pragma unroll
    for (int ni = 0; ni < 2; ++ni) acc[mi][ni] = (f32x4){0.f, 0.f, 0.f, 0.f};

  auto STAGE = [&](int buf, int k0) {
#pragma unroll
    for (int pass = 0; pass < 2; ++pass) {
      int rbase = pass * 64 + w * 8;
      int row = rbase + (lane >> 3);
      int ul = (lane & 7) ^ (row & 7);
      gload_lds16(A + (size_t)(m0 + row) * 768 + k0 + ul * 8, Als[buf] + rbase * 64);
      gload_lds16(Bt + (size_t)(n0 + row) * 768 + k0 + ul * 8, Bls[buf] + rbase * 64);
    }
  };

  STAGE(0, 0);
  asm volatile("s_waitcnt vmcnt(0)" ::: "memory");
  __builtin_amdgcn_sched_barrier(0);
  __builtin_amdgcn_s_barrier();

  for (int t = 0; t < 12; ++t) {
    if (t < 11) STAGE((t + 1) & 1, (t + 1) * 64);   // loads fly during compute
    const short* Ab = Als[t & 1];
    const short* Bb = Bls[t & 1];
    __builtin_amdgcn_s_setprio(1);
#pragma unroll
    for (int kk = 0; kk < 2; ++kk) {
      bf16x8 af[4], bfv[2];
#pragma unroll
      for (int mi = 0; mi < 4; ++mi) {
        int row = wr + mi * 16 + (lane & 15);
        int off = (row * 128 + kk * 64 + (lane >> 4) * 16) ^ ((row & 7) << 4);
        af[mi] = *(const bf16x8*)((const char*)Ab + off);
      }
#pragma unroll
      for (int ni = 0; ni < 2; ++ni) {
        int row = wc + ni * 16 + (lane & 15);
        int off = (row * 128 + kk * 64 + (lane >> 4) * 16) ^ ((row & 7) << 4);
        bfv[ni] = *(const bf16x8*)((const char*)Bb + off);
      }
#pragma unroll
      for (int mi = 0; mi < 4; ++mi)
#pragma unroll
        for (int ni = 0; ni < 2; ++ni)
          acc[mi][ni] = __builtin_amdgcn_mfma_f32_16x16x32_bf16(
              af[mi], bfv[ni], acc[mi][ni], 0, 0, 0);
    }
    __builtin_amdgcn_s_setprio(0);
    if (t < 11) {
      // own stage(t+1) proven landed before the publishing barrier
      asm volatile("s_waitcnt vmcnt(0)" ::: "memory");
      __builtin_amdgcn_sched_barrier(0);
      __builtin_amdgcn_s_barrier();
    }
  }

  if (MODE == 1) {
    // block-uniform third: n0 multiple of 128, 128 | 768
    const int three = n0 / 768;
    const int nb = n0 - three * 768;
#pragma unroll
    for (int mi = 0; mi < 4; ++mi)
#pragma unroll
      for (int ni = 0; ni < 2; ++ni)
#pragma unroll
        for (int j = 0; j < 4; ++j) {
          int row = m0 + wr + mi * 16 + ((lane >> 4) << 2) + j;
          int col = n0 + wc + ni * 16 + (lane & 15);
          float v = acc[mi][ni][j] + bias[col];
          int rem = nb + wc + ni * 16 + (lane & 15);
          int hh = rem >> 6, d = rem & 63;
          int b = row >> 10, n = row & 1023;
          size_t bh = (size_t)(b * 12 + hh);
          if (three == 0)      outQ[(bh * 1024 + n) * 64 + d] = (short)f2bf(v * QSCALE);
          else if (three == 1) outK[(bh * 1024 + n) * 64 + d] = (short)f2bf(v);
          else                 outVT[(bh * 64 + d) * 1024 + n] = (short)f2bf(v);
        }
  } else {
#pragma unroll
    for (int mi = 0; mi < 4; ++mi)
#pragma unroll
      for (int ni = 0; ni < 2; ++ni)
#pragma unroll
        for (int j = 0; j < 4; ++j) {
          int row = m0 + wr + mi * 16 + ((lane >> 4) << 2) + j;
          int col = n0 + wc + ni * 16 + (lane & 15);
          outF[(size_t)row * 768 + col] = acc[mi][ni][j] + bias[col];
        }
  }
}

// build one PV B-frag (4 u32 = 8 bf16, k = kv) from packed P pairs:
// permlane32_swap(x=pk[m][p], y=pk[m+1][p]) -> x' = frag reg (own|swap),
// y' = frag reg (swap|own) for the two lane halves. 4 swaps per 32-kv block.
#define MKFRAG(B, pA, pB, pC, pD)                                    \
  { unsigned x0 = (pA), y0 = (pC), x1 = (pB), y1 = (pD);             \
    asm("v_permlane32_swap_b32 %0, %1" : "+v"(x0), "+v"(y0));        \
    asm("v_permlane32_swap_b32 %0, %1" : "+v"(x1), "+v"(y1));        \
    B.u[0] = x0; B.u[1] = x1; B.u[2] = y0; B.u[3] = y1; }

// Flash attention, 32x32x16 MFMA, swapped QK^T, fixed-shift softmax,
// permlane32_swap P-redistribute, distance-2 KV pipeline, coalesced
// pre-swizzled bf16 pos (QSCALE folded), h-major XCD swizzle.
// grid: 768 blocks x 256 threads; 4 waves x 32 q-rows (QBLK=128).
__global__ __launch_bounds__(256, 3) void attn_kernel(
    const short* __restrict__ qb, const short* __restrict__ kb,
    const short* __restrict__ vtb, const short* __restrict__ posb,
    short* __restrict__ outb) {
  // h-major XCD swizzle: the 8 same-(h,qblk) diff-b blocks share one XCD L2.
  const int bid = blockIdx.x;
  const int lb = (bid & 7) * 96 + (bid >> 3);
  const int qblk = lb & 7;
  const int hb = lb >> 3;            // 0..95 = h*8 + b
  const int h = hb >> 3, b = hb & 7;

  const int tid = threadIdx.x, lane = tid & 63, w = tid >> 6;
  const int c5 = lane & 31, g1 = lane >> 5;
  const size_t bh = (size_t)(b * 12 + h);
  const short* Q = qb + bh * SEQ * 64;
  const short* K = kb + bh * SEQ * 64;
  const short* VT = vtb + bh * 64 * SEQ;
  const int q0w = qblk * 128 + w * 32;

  // per-(block,wave,lane) base into pre-swizzled pos (shorts)
  const short* pwb = posb + (size_t)h * 1048576 + (size_t)qblk * 131072
                     + w * 2048 + lane * 8;

  __shared__ short kls[3 * 4096];
  __shared__ short vls[3 * 4096];

  // Q as B-operand of 32x32x16: B[k=16kd+8g1+i][col q=c5]; Q pre-scaled.
  bf16x8 qf[4];
#pragma unroll
  for (int kd = 0; kd < 4; ++kd)
    qf[kd] = *(const bf16x8*)(Q + (size_t)(q0w + c5) * 64 + kd * 16 + g1 * 8);

  f32x16 o0, o1;    // O^T: rows d = (r&3)+8*(r>>2)+4g1 (+32 for o1), col q=c5
#pragma unroll
  for (int i = 0; i < 16; ++i) { o0[i] = 0.f; o1[i] = 0.f; }
  float lsum = 0.f;

  // 4-wave STAGE: 2 K + 2 V gload_lds per thread (wave w: rows 8w..8w+7, +32)
  auto STAGE = [&](short* kb_, short* vb_, int kv0) {
    int r0 = w * 8 + (lane >> 3);
    int u0 = (lane & 7) ^ (r0 & 7);
    gload_lds16(K + (size_t)(kv0 + r0) * 64 + u0 * 8, kb_ + w * 512);
    gload_lds16(K + (size_t)(kv0 + 32 + r0) * 64 + u0 * 8, kb_ + 2048 + w * 512);
    gload_lds16(VT + (size_t)r0 * SEQ + kv0 + u0 * 8, vb_ + w * 512);
    gload_lds16(VT + (size_t)(32 + r0) * SEQ + kv0 + u0 * 8, vb_ + 2048 + w * 512);
  };

  short* kbuf0 = kls;        short* vbuf0 = vls;
  short* kbuf1 = kls + 4096; short* vbuf1 = vls + 4096;
  short* kbuf2 = kls + 8192; short* vbuf2 = vls + 8192;

  STAGE(kbuf0, vbuf0, 0);
  STAGE(kbuf1, vbuf1, 64);
  asm volatile("s_waitcnt vmcnt(4)" ::: "memory");   // stage(0) landed
  __builtin_amdgcn_sched_barrier(0);
  __builtin_amdgcn_s_barrier();

  for (int ti = 0; ti < 16; ++ti) {
    const int kv0 = ti * 64;

    // coalesced pos loads (4 x 16B, wave-dense), consumed in softmax
    union { bf16x8 v; unsigned u[4]; } ua0, ua1, ub0, ub1;
    ua0.v = *(const bf16x8*)(pwb + ti * 8192);          // i0=0, jh=0 -> r=0..7
    ua1.v = *(const bf16x8*)(pwb + ti * 8192 + 512);    // i0=0, jh=1 -> r=8..15
    ub0.v = *(const bf16x8*)(pwb + ti * 8192 + 1024);   // i0=1, jh=0
    ub1.v = *(const bf16x8*)(pwb + ti * 8192 + 1536);   // i0=1, jh=1
    asm volatile("" ::: "memory");   // pin pos-issue before STAGE
    if (ti < 14) STAGE(kbuf2, vbuf2, kv0 + 128);

    const short* kc = kbuf0;
    const short* vc = vbuf0;

    // QK^T swapped: A = K rows kv (2 blocks of 32), B = Q cols q.
    f32x16 p0, p1;
#pragma unroll
    for (int i = 0; i < 16; ++i) { p0[i] = 0.f; p1[i] = 0.f; }
    __builtin_amdgcn_s_setprio(1);
#pragma unroll
    for (int kd = 0; kd < 4; ++kd) {
      int off0 = (c5 * 128 + kd * 32 + g1 * 16) ^ ((c5 & 7) << 4);
      int off1 = ((32 + c5) * 128 + kd * 32 + g1 * 16) ^ ((c5 & 7) << 4);
      bf16x8 kf0 = *(const bf16x8*)((const char*)kc + off0);
      bf16x8 kf1 = *(const bf16x8*)((const char*)kc + off1);
      p0 = __builtin_amdgcn_mfma_f32_32x32x16_bf16(kf0, qf[kd], p0, 0, 0, 0);
      p1 = __builtin_amdgcn_mfma_f32_32x32x16_bf16(kf1, qf[kd], p1, 0, 0, 0);
    }
    __builtin_amdgcn_s_setprio(0);

    // P = exp2(qk + pos); reg r: kv = (r&3)+8*(r>>2)+4g1 (+32 for p1)
#pragma unroll
    for (int r = 0; r < 16; ++r) {
      unsigned wa = (r < 8) ? ua0.u[(r >> 1) & 3] : ua1.u[(r >> 1) & 3];
      unsigned wb = (r < 8) ? ub0.u[(r >> 1) & 3] : ub1.u[(r >> 1) & 3];
      float a = exp2f(p0[r] + bfsel(wa, r & 1));
      float bq = exp2f(p1[r] + bfsel(wb, r & 1));
      p0[r] = a; p1[r] = bq;
      lsum += a + bq;
    }

    // pack pairs along j: pk[2m+p] = (kv=8m+4g1+2p, +1)
    unsigned pk0[8], pk1[8];
#pragma unroll
    for (int m = 0; m < 4; ++m) {
      pk0[2 * m]     = cvtpk(p0[4 * m],     p0[4 * m + 1]);
      pk0[2 * m + 1] = cvtpk(p0[4 * m + 2], p0[4 * m + 3]);
      pk1[2 * m]     = cvtpk(p1[4 * m],     p1[4 * m + 1]);
      pk1[2 * m + 1] = cvtpk(p1[4 * m + 2], p1[4 * m + 3]);
    }

    // PV B-frags: step s covers kv 16s..16s+15; k = 8g1+i
    union bb { bf16x8 v; unsigned u[4]; } B0, B1, B2, B3;
    MKFRAG(B0, pk0[0], pk0[1], pk0[2], pk0[3]);   // s=0
    MKFRAG(B1, pk0[4], pk0[5], pk0[6], pk0[7]);   // s=1
    MKFRAG(B2, pk1[0], pk1[1], pk1[2], pk1[3]);   // s=2
    MKFRAG(B3, pk1[4], pk1[5], pk1[6], pk1[7]);   // s=3

    // PV: O^T += V^T (A, rows d) x P^T (B, cols q)
    __builtin_amdgcn_s_setprio(1);
#define PVSTEP(Bv, s)                                                        \
    { int o0f = (c5 * 128 + (s) * 32 + g1 * 16) ^ ((c5 & 7) << 4);           \
      int o1f = ((32 + c5) * 128 + (s) * 32 + g1 * 16) ^ ((c5 & 7) << 4);    \
      bf16x8 vf0 = *(const bf16x8*)((const char*)vc + o0f);                  \
      bf16x8 vf1 = *(const bf16x8*)((const char*)vc + o1f);                  \
      o0 = __builtin_amdgcn_mfma_f32_32x32x16_bf16(vf0, Bv.v, o0, 0, 0, 0);  \
      o1 = __builtin_amdgcn_mfma_f32_32x32x16_bf16(vf1, Bv.v, o1, 0, 0, 0); }
    PVSTEP(B0, 0); PVSTEP(B1, 1); PVSTEP(B2, 2); PVSTEP(B3, 3);
#undef PVSTEP
    __builtin_amdgcn_s_setprio(0);

    // rotate buffers
    short* tk = kbuf0; kbuf0 = kbuf1; kbuf1 = kbuf2; kbuf2 = tk;
    short* tv = vbuf0; vbuf0 = vbuf1; vbuf1 = vbuf2; vbuf2 = tv;

    // pos consumed above -> only stage(ti+2)[4] may remain in flight.
    if (ti < 15) {
      if (ti < 14) asm volatile("s_waitcnt vmcnt(4)" ::: "memory");
      else         asm volatile("s_waitcnt vmcnt(0)" ::: "memory");
      __builtin_amdgcn_sched_barrier(0);
      __builtin_amdgcn_s_barrier();
    }
  }

  // lane and lane^32 hold complementary kv rows of the same q-column
  lsum += __shfl_xor(lsum, 32);
  float inv = 1.0f / lsum;
  size_t obase = (size_t)(b * SEQ + q0w + c5) * 768 + h * 64 + g1 * 4;
#pragma unroll
  for (int m = 0; m < 4; ++m) {
    short4v ov0, ov1;
#pragma unroll
    for (int j = 0; j < 4; ++j) {
      ov0[j] = (short)f2bf(o0[4 * m + j] * inv);
      ov1[j] = (short)f2bf(o1[4 * m + j] * inv);
    }
    *(short4v*)(outb + obase + m * 8) = ov0;
    *(short4v*)(outb + obase + 32 + m * 8) = ov1;
  }
}

extern "C" void kernel_launch(void* const* d_in, const int* in_sizes, int n_in,
                              void* d_out, int out_size, void* d_ws, size_t ws_size,
                              hipStream_t stream) {
  const float* x      = (const float*)d_in[0];
  const float* pos    = (const float*)d_in[1];
  const float* W_qkv  = (const float*)d_in[2];
  const float* b_qkv  = (const float*)d_in[3];
  const float* W_proj = (const float*)d_in[4];
  const float* b_proj = (const float*)d_in[5];
  float* out = (float*)d_out;

  char* ws = (char*)d_ws;
  short* A       = (short*)(ws);                  // 12,582,912 (consumed by gemm<1>)
  short* attnbuf = (short*)(ws);                  // alias of A (written after)
  short* Bt      = (short*)(ws + 12582912);       //  3,538,944
  short* wpt     = (short*)(ws + 16121856);       //  1,179,648
  short* qbuf    = (short*)(ws + 17301504);       // 12,582,912
  short* kbuf    = (short*)(ws + 29884416);       // 12,582,912
  short* vtbuf   = (short*)(ws + 42467328);       // 12,582,912
  short* posb    = (short*)(ws + 55050240);       // 25,165,824
  // total: 80,216,064 bytes

  prep_x_kernel<<<6144, 256, 0, stream>>>(x, A);
  prep_w_kernel<<<dim3(12, 36), 256, 0, stream>>>(W_qkv, Bt);
  prep_wp_kernel<<<dim3(12, 12), 256, 0, stream>>>(W_proj, wpt);
  prep_pos_kernel<<<6144, 256, 0, stream>>>(pos, posb);
  gemm_kernel<1><<<1152, 512, 0, stream>>>(A, Bt, b_qkv,
                                           qbuf, kbuf, vtbuf, nullptr);
  attn_kernel<<<768, 256, 0, stream>>>(qbuf, kbuf, vtbuf, posb, attnbuf);
  gemm_kernel<2><<<384, 512, 0, stream>>>(attnbuf, wpt, b_proj,
                                          nullptr, nullptr, nullptr, out);
}

// Round 11
// 151.705 us; speedup vs baseline: 1.7399x; 1.0057x over previous
//
#include <hip/hip_runtime.h>

#define SEQ   1024
#define HEADS 12
#define CDIM  768
#define BATCH 8

// 0.125 * log2(e): folds the 1/sqrt(64) score scale and the exp->exp2 change
#define QSCALE 0.18033688011112042f

typedef __attribute__((ext_vector_type(8))) short bf16x8;
typedef __attribute__((ext_vector_type(4))) float f32x4;
typedef __attribute__((ext_vector_type(16))) float f32x16;
typedef __attribute__((ext_vector_type(4))) float float4v;
typedef __attribute__((ext_vector_type(4))) short short4v;

__device__ __forceinline__ void gload_lds16(const void* g, void* l) {
  __builtin_amdgcn_global_load_lds(
      (const __attribute__((address_space(1))) unsigned int*)g,
      (__attribute__((address_space(3))) unsigned int*)l, 16, 0, 0);
}

__device__ __forceinline__ unsigned short f2bf(float f) {
  union { float f; unsigned u; } v; v.f = f;
  unsigned r = v.u + 0x7fff + ((v.u >> 16) & 1);
  return (unsigned short)(r >> 16);
}

// pack two f32 -> u32 of 2x bf16 (lo = a, hi = b); no builtin on gfx950
__device__ __forceinline__ unsigned cvtpk(float a, float b) {
  unsigned r;
  asm("v_cvt_pk_bf16_f32 %0, %1, %2" : "=v"(r) : "v"(a), "v"(b));
  return r;
}

// select bf16 half of a packed u32 as f32 (odd -> high half, even -> low)
__device__ __forceinline__ float bfsel(unsigned u, int odd) {
  union { unsigned u; float f; } v;
  v.u = odd ? (u & 0xffff0000u) : (u << 16);
  return v.f;
}

// x [8192,768] f32 -> A [8192,768] bf16
__global__ __launch_bounds__(256) void prep_x_kernel(const float* __restrict__ x,
                                                     short* __restrict__ A) {
  int i = blockIdx.x * 256 + threadIdx.x;
  int r = i / 192;
  int c4 = (i % 192) * 4;
  float4v xv = *(const float4v*)(x + (size_t)r * 768 + c4);
  short4v hi;
#pragma unroll
  for (int j = 0; j < 4; ++j) hi[j] = (short)f2bf(xv[j]);
  *(short4v*)(A + (size_t)r * 768 + c4) = hi;
}

// W_qkv [768,2304] f32 -> Bt [2304,768] bf16 transposed
__global__ __launch_bounds__(256) void prep_w_kernel(const float* __restrict__ W,
                                                     short* __restrict__ Bt) {
  __shared__ float tile[64][65];
  int k0 = blockIdx.x * 64;
  int n0 = blockIdx.y * 64;
  int t = threadIdx.x;
#pragma unroll
  for (int it = 0; it < 16; ++it) {
    int r = it * 4 + (t >> 6);
    int c = t & 63;
    tile[r][c] = W[(size_t)(k0 + r) * 2304 + n0 + c];
  }
  __syncthreads();
#pragma unroll
  for (int it = 0; it < 16; ++it) {
    int nr = it * 4 + (t >> 6);
    int kc = t & 63;
    Bt[(size_t)(n0 + nr) * 768 + k0 + kc] = (short)f2bf(tile[kc][nr]);
  }
}

// W_proj [768,768] f32 -> Wpt [768,768] bf16 transposed
__global__ __launch_bounds__(256) void prep_wp_kernel(const float* __restrict__ W,
                                                      short* __restrict__ Bt) {
  __shared__ float tile[64][65];
  int k0 = blockIdx.x * 64;
  int n0 = blockIdx.y * 64;
  int t = threadIdx.x;
#pragma unroll
  for (int it = 0; it < 16; ++it) {
    int r = it * 4 + (t >> 6);
    int c = t & 63;
    tile[r][c] = W[(size_t)(k0 + r) * 768 + n0 + c];
  }
  __syncthreads();
#pragma unroll
  for (int it = 0; it < 16; ++it) {
    int nr = it * 4 + (t >> 6);
    int kc = t & 63;
    Bt[(size_t)(n0 + nr) * 768 + k0 + kc] = (short)f2bf(tile[kc][nr]);
  }
}

// pos [12,1024,1024] f32 -> posb bf16 (QSCALE-folded), pre-swizzled to the
// attn kernel's per-lane register order (each element consumed exactly once).
__global__ __launch_bounds__(256) void prep_pos_kernel(const float* __restrict__ P,
                                                       short* __restrict__ PB) {
  int t = blockIdx.x * 256 + threadIdx.x;   // 12<<17 = 1,572,864 threads
  int lane = t & 63;
  int jh   = (t >> 6) & 1;
  int i0   = (t >> 7) & 1;
  int w    = (t >> 8) & 3;
  int ti   = (t >> 10) & 15;
  int qblk = (t >> 14) & 7;
  int h    = t >> 17;
  int c5 = lane & 31, g1 = lane >> 5;
  int q = qblk * 128 + w * 32 + c5;
  const float* src = P + ((size_t)h * SEQ + q) * SEQ
                     + ti * 64 + i0 * 32 + 4 * g1 + 16 * jh;
  float4v v0 = *(const float4v*)(src);       // jl = 0..3  (kv +0..3)
  float4v v1 = *(const float4v*)(src + 8);   // jl = 4..7  (kv +8..11)
  union { short s[8]; bf16x8 v; } o;
#pragma unroll
  for (int p = 0; p < 4; ++p) {
    o.s[p]     = (short)f2bf(v0[p] * QSCALE);
    o.s[4 + p] = (short)f2bf(v1[p] * QSCALE);
  }
  *(bf16x8*)(PB + (size_t)t * 8) = o.v;
}

// 128x192-tile GEMM, BK=64, K=768, 8 waves (2 row x 4 col, 64x48 each),
// 16x16x32 bf16 MFMA. Distance-2 staging over 3 LDS buffers (120 KB),
// counted vmcnt(5): stage(t+2) stays in flight across ~2 K-steps.
// XCD-chunked linear grid. MODE 1: qkv (N=2304, 12 n-blocks, 768 blocks);
// MODE 2: proj (N=768, 4 n-blocks, 256 blocks = one exact round).
template <int MODE>
__global__ __launch_bounds__(512, 2) void gemm_kernel(
    const short* __restrict__ A, const short* __restrict__ Bt,
    const float* __restrict__ bias,
    short* __restrict__ outQ, short* __restrict__ outK, short* __restrict__ outVT,
    float* __restrict__ outF) {
  constexpr int NBLK = (MODE == 1) ? 12 : 4;    // n-blocks per m-row
  constexpr int CHUNK = (MODE == 1) ? 96 : 32;  // nwg/8
  const int bid = blockIdx.x;
  const int lb = (bid & 7) * CHUNK + (bid >> 3); // XCD-chunked, bijective
  const int n0 = (lb % NBLK) * 192;
  const int m0 = (lb / NBLK) * 128;

  // per buffer: A 128x64 (8192 sh) + B 192x64 (12288 sh) = 20480 sh = 40 KB
  __shared__ short lds[3 * 20480];

  const int tid = threadIdx.x;
  const int lane = tid & 63;
  const int w = tid >> 6;
  const int wr = (w & 1) * 64;       // 2 row-groups of 64
  const int wc = (w >> 1) * 48;      // 4 col-groups of 48
  f32x4 acc[4][3];
#pragma unroll
  for (int mi = 0; mi < 4; ++mi)
#pragma unroll
    for (int ni = 0; ni < 3; ++ni) acc[mi][ni] = (f32x4){0.f, 0.f, 0.f, 0.f};

  // 5 gload_lds per thread per stage: 2 A-segments + 3 B-segments of 64 rows
  auto STAGE = [&](int buf, int k0) {
    short* base = lds + buf * 20480;
    int rowlow = w * 8 + (lane >> 3);             // 0..63
    int ul = (lane & 7) ^ (rowlow & 7);           // row&7 == rowlow&7 (64-aligned segs)
#pragma unroll
    for (int seg = 0; seg < 2; ++seg)
      gload_lds16(A + (size_t)(m0 + seg * 64 + rowlow) * 768 + k0 + ul * 8,
                  base + (seg * 64 + w * 8) * 64);
#pragma unroll
    for (int seg = 0; seg < 3; ++seg)
      gload_lds16(Bt + (size_t)(n0 + seg * 64 + rowlow) * 768 + k0 + ul * 8,
                  base + 8192 + (seg * 64 + w * 8) * 64);
  };

  STAGE(0, 0);
  STAGE(1, 64);
  asm volatile("s_waitcnt vmcnt(5)" ::: "memory");   // stage(0) landed
  __builtin_amdgcn_sched_barrier(0);
  __builtin_amdgcn_s_barrier();

  for (int t = 0; t < 12; ++t) {
    if (t < 10) STAGE((t + 2) % 3, (t + 2) * 64);   // 2 steps in flight
    const char* Ab = (const char*)(lds + (t % 3) * 20480);
    const char* Bb = Ab + 16384;
    __builtin_amdgcn_s_setprio(1);
#pragma unroll
    for (int kk = 0; kk < 2; ++kk) {
      bf16x8 af[4], bfv[3];
#pragma unroll
      for (int mi = 0; mi < 4; ++mi) {
        int row = wr + mi * 16 + (lane & 15);
        int off = (row * 128 + kk * 64 + (lane >> 4) * 16) ^ ((row & 7) << 4);
        af[mi] = *(const bf16x8*)(Ab + off);
      }
#pragma unroll
      for (int ni = 0; ni < 3; ++ni) {
        int row = wc + ni * 16 + (lane & 15);
        int off = (row * 128 + kk * 64 + (lane >> 4) * 16) ^ ((row & 7) << 4);
        bfv[ni] = *(const bf16x8*)(Bb + off);
      }
#pragma unroll
      for (int mi = 0; mi < 4; ++mi)
#pragma unroll
        for (int ni = 0; ni < 3; ++ni)
          acc[mi][ni] = __builtin_amdgcn_mfma_f32_16x16x32_bf16(
              af[mi], bfv[ni], acc[mi][ni], 0, 0, 0);
    }
    __builtin_amdgcn_s_setprio(0);
    if (t < 11) {
      // prove own stage(t+1) landed; allow stage(t+2)'s 5 to stay in flight
      if (t < 10) asm volatile("s_waitcnt vmcnt(5)" ::: "memory");
      else        asm volatile("s_waitcnt vmcnt(0)" ::: "memory");
      __builtin_amdgcn_sched_barrier(0);
      __builtin_amdgcn_s_barrier();
    }
  }

  if (MODE == 1) {
    // 192 | 768 per-block third: n0 multiple of 192, each block in one third
    const int three = n0 / 768;
    const int nb = n0 - three * 768;
#pragma unroll
    for (int mi = 0; mi < 4; ++mi)
#pragma unroll
      for (int ni = 0; ni < 3; ++ni)
#pragma unroll
        for (int j = 0; j < 4; ++j) {
          int row = m0 + wr + mi * 16 + ((lane >> 4) << 2) + j;
          int col = n0 + wc + ni * 16 + (lane & 15);
          float v = acc[mi][ni][j] + bias[col];
          int rem = nb + wc + ni * 16 + (lane & 15);
          int hh = rem >> 6, d = rem & 63;
          int b = row >> 10, n = row & 1023;
          size_t bh = (size_t)(b * 12 + hh);
          if (three == 0)      outQ[(bh * 1024 + n) * 64 + d] = (short)f2bf(v * QSCALE);
          else if (three == 1) outK[(bh * 1024 + n) * 64 + d] = (short)f2bf(v);
          else                 outVT[(bh * 64 + d) * 1024 + n] = (short)f2bf(v);
        }
  } else {
#pragma unroll
    for (int mi = 0; mi < 4; ++mi)
#pragma unroll
      for (int ni = 0; ni < 3; ++ni)
#pragma unroll
        for (int j = 0; j < 4; ++j) {
          int row = m0 + wr + mi * 16 + ((lane >> 4) << 2) + j;
          int col = n0 + wc + ni * 16 + (lane & 15);
          outF[(size_t)row * 768 + col] = acc[mi][ni][j] + bias[col];
        }
  }
}

// build one PV B-frag (4 u32 = 8 bf16, k = kv) from packed P pairs:
// permlane32_swap(x=pk[m][p], y=pk[m+1][p]) -> x' = frag reg (own|swap),
// y' = frag reg (swap|own) for the two lane halves. 4 swaps per 32-kv block.
#define MKFRAG(B, pA, pB, pC, pD)                                    \
  { unsigned x0 = (pA), y0 = (pC), x1 = (pB), y1 = (pD);             \
    asm("v_permlane32_swap_b32 %0, %1" : "+v"(x0), "+v"(y0));        \
    asm("v_permlane32_swap_b32 %0, %1" : "+v"(x1), "+v"(y1));        \
    B.u[0] = x0; B.u[1] = x1; B.u[2] = y0; B.u[3] = y1; }

// Flash attention, 32x32x16 MFMA, swapped QK^T, fixed-shift softmax,
// permlane32_swap P-redistribute, distance-2 KV pipeline, coalesced
// pre-swizzled bf16 pos (QSCALE folded), h-major XCD swizzle.
// grid: 768 blocks x 256 threads; 4 waves x 32 q-rows (QBLK=128).
__global__ __launch_bounds__(256, 3) void attn_kernel(
    const short* __restrict__ qb, const short* __restrict__ kb,
    const short* __restrict__ vtb, const short* __restrict__ posb,
    short* __restrict__ outb) {
  // h-major XCD swizzle: the 8 same-(h,qblk) diff-b blocks share one XCD L2.
  const int bid = blockIdx.x;
  const int lb = (bid & 7) * 96 + (bid >> 3);
  const int qblk = lb & 7;
  const int hb = lb >> 3;            // 0..95 = h*8 + b
  const int h = hb >> 3, b = hb & 7;

  const int tid = threadIdx.x, lane = tid & 63, w = tid >> 6;
  const int c5 = lane & 31, g1 = lane >> 5;
  const size_t bh = (size_t)(b * 12 + h);
  const short* Q = qb + bh * SEQ * 64;
  const short* K = kb + bh * SEQ * 64;
  const short* VT = vtb + bh * 64 * SEQ;
  const int q0w = qblk * 128 + w * 32;

  // per-(block,wave,lane) base into pre-swizzled pos (shorts)
  const short* pwb = posb + (size_t)h * 1048576 + (size_t)qblk * 131072
                     + w * 2048 + lane * 8;

  __shared__ short kls[3 * 4096];
  __shared__ short vls[3 * 4096];

  // Q as B-operand of 32x32x16: B[k=16kd+8g1+i][col q=c5]; Q pre-scaled.
  bf16x8 qf[4];
#pragma unroll
  for (int kd = 0; kd < 4; ++kd)
    qf[kd] = *(const bf16x8*)(Q + (size_t)(q0w + c5) * 64 + kd * 16 + g1 * 8);

  f32x16 o0, o1;    // O^T: rows d = (r&3)+8*(r>>2)+4g1 (+32 for o1), col q=c5
#pragma unroll
  for (int i = 0; i < 16; ++i) { o0[i] = 0.f; o1[i] = 0.f; }
  float lsum = 0.f;

  // 4-wave STAGE: 2 K + 2 V gload_lds per thread (wave w: rows 8w..8w+7, +32)
  auto STAGE = [&](short* kb_, short* vb_, int kv0) {
    int r0 = w * 8 + (lane >> 3);
    int u0 = (lane & 7) ^ (r0 & 7);
    gload_lds16(K + (size_t)(kv0 + r0) * 64 + u0 * 8, kb_ + w * 512);
    gload_lds16(K + (size_t)(kv0 + 32 + r0) * 64 + u0 * 8, kb_ + 2048 + w * 512);
    gload_lds16(VT + (size_t)r0 * SEQ + kv0 + u0 * 8, vb_ + w * 512);
    gload_lds16(VT + (size_t)(32 + r0) * SEQ + kv0 + u0 * 8, vb_ + 2048 + w * 512);
  };

  short* kbuf0 = kls;        short* vbuf0 = vls;
  short* kbuf1 = kls + 4096; short* vbuf1 = vls + 4096;
  short* kbuf2 = kls + 8192; short* vbuf2 = vls + 8192;

  STAGE(kbuf0, vbuf0, 0);
  STAGE(kbuf1, vbuf1, 64);
  asm volatile("s_waitcnt vmcnt(4)" ::: "memory");   // stage(0) landed
  __builtin_amdgcn_sched_barrier(0);
  __builtin_amdgcn_s_barrier();

  for (int ti = 0; ti < 16; ++ti) {
    const int kv0 = ti * 64;

    // coalesced pos loads (4 x 16B, wave-dense), consumed in softmax
    union { bf16x8 v; unsigned u[4]; } ua0, ua1, ub0, ub1;
    ua0.v = *(const bf16x8*)(pwb + ti * 8192);          // i0=0, jh=0 -> r=0..7
    ua1.v = *(const bf16x8*)(pwb + ti * 8192 + 512);    // i0=0, jh=1 -> r=8..15
    ub0.v = *(const bf16x8*)(pwb + ti * 8192 + 1024);   // i0=1, jh=0
    ub1.v = *(const bf16x8*)(pwb + ti * 8192 + 1536);   // i0=1, jh=1
    asm volatile("" ::: "memory");   // pin pos-issue before STAGE
    if (ti < 14) STAGE(kbuf2, vbuf2, kv0 + 128);

    const short* kc = kbuf0;
    const short* vc = vbuf0;

    // QK^T swapped: A = K rows kv (2 blocks of 32), B = Q cols q.
    f32x16 p0, p1;
#pragma unroll
    for (int i = 0; i < 16; ++i) { p0[i] = 0.f; p1[i] = 0.f; }
    __builtin_amdgcn_s_setprio(1);
#pragma unroll
    for (int kd = 0; kd < 4; ++kd) {
      int off0 = (c5 * 128 + kd * 32 + g1 * 16) ^ ((c5 & 7) << 4);
      int off1 = ((32 + c5) * 128 + kd * 32 + g1 * 16) ^ ((c5 & 7) << 4);
      bf16x8 kf0 = *(const bf16x8*)((const char*)kc + off0);
      bf16x8 kf1 = *(const bf16x8*)((const char*)kc + off1);
      p0 = __builtin_amdgcn_mfma_f32_32x32x16_bf16(kf0, qf[kd], p0, 0, 0, 0);
      p1 = __builtin_amdgcn_mfma_f32_32x32x16_bf16(kf1, qf[kd], p1, 0, 0, 0);
    }
    __builtin_amdgcn_s_setprio(0);

    // P = exp2(qk + pos); reg r: kv = (r&3)+8*(r>>2)+4g1 (+32 for p1)
#pragma unroll
    for (int r = 0; r < 16; ++r) {
      unsigned wa = (r < 8) ? ua0.u[(r >> 1) & 3] : ua1.u[(r >> 1) & 3];
      unsigned wb = (r < 8) ? ub0.u[(r >> 1) & 3] : ub1.u[(r >> 1) & 3];
      float a = exp2f(p0[r] + bfsel(wa, r & 1));
      float bq = exp2f(p1[r] + bfsel(wb, r & 1));
      p0[r] = a; p1[r] = bq;
      lsum += a + bq;
    }

    // pack pairs along j: pk[2m+p] = (kv=8m+4g1+2p, +1)
    unsigned pk0[8], pk1[8];
#pragma unroll
    for (int m = 0; m < 4; ++m) {
      pk0[2 * m]     = cvtpk(p0[4 * m],     p0[4 * m + 1]);
      pk0[2 * m + 1] = cvtpk(p0[4 * m + 2], p0[4 * m + 3]);
      pk1[2 * m]     = cvtpk(p1[4 * m],     p1[4 * m + 1]);
      pk1[2 * m + 1] = cvtpk(p1[4 * m + 2], p1[4 * m + 3]);
    }

    // PV B-frags: step s covers kv 16s..16s+15; k = 8g1+i
    union bb { bf16x8 v; unsigned u[4]; } B0, B1, B2, B3;
    MKFRAG(B0, pk0[0], pk0[1], pk0[2], pk0[3]);   // s=0
    MKFRAG(B1, pk0[4], pk0[5], pk0[6], pk0[7]);   // s=1
    MKFRAG(B2, pk1[0], pk1[1], pk1[2], pk1[3]);   // s=2
    MKFRAG(B3, pk1[4], pk1[5], pk1[6], pk1[7]);   // s=3

    // PV: O^T += V^T (A, rows d) x P^T (B, cols q)
    __builtin_amdgcn_s_setprio(1);
#define PVSTEP(Bv, s)                                                        \
    { int o0f = (c5 * 128 + (s) * 32 + g1 * 16) ^ ((c5 & 7) << 4);           \
      int o1f = ((32 + c5) * 128 + (s) * 32 + g1 * 16) ^ ((c5 & 7) << 4);    \
      bf16x8 vf0 = *(const bf16x8*)((const char*)vc + o0f);                  \
      bf16x8 vf1 = *(const bf16x8*)((const char*)vc + o1f);                  \
      o0 = __builtin_amdgcn_mfma_f32_32x32x16_bf16(vf0, Bv.v, o0, 0, 0, 0);  \
      o1 = __builtin_amdgcn_mfma_f32_32x32x16_bf16(vf1, Bv.v, o1, 0, 0, 0); }
    PVSTEP(B0, 0); PVSTEP(B1, 1); PVSTEP(B2, 2); PVSTEP(B3, 3);
#undef PVSTEP
    __builtin_amdgcn_s_setprio(0);

    // rotate buffers
    short* tk = kbuf0; kbuf0 = kbuf1; kbuf1 = kbuf2; kbuf2 = tk;
    short* tv = vbuf0; vbuf0 = vbuf1; vbuf1 = vbuf2; vbuf2 = tv;

    // pos consumed above -> only stage(ti+2)[4] may remain in flight.
    if (ti < 15) {
      if (ti < 14) asm volatile("s_waitcnt vmcnt(4)" ::: "memory");
      else         asm volatile("s_waitcnt vmcnt(0)" ::: "memory");
      __builtin_amdgcn_sched_barrier(0);
      __builtin_amdgcn_s_barrier();
    }
  }

  // lane and lane^32 hold complementary kv rows of the same q-column
  lsum += __shfl_xor(lsum, 32);
  float inv = 1.0f / lsum;
  size_t obase = (size_t)(b * SEQ + q0w + c5) * 768 + h * 64 + g1 * 4;
#pragma unroll
  for (int m = 0; m < 4; ++m) {
    short4v ov0, ov1;
#pragma unroll
    for (int j = 0; j < 4; ++j) {
      ov0[j] = (short)f2bf(o0[4 * m + j] * inv);
      ov1[j] = (short)f2bf(o1[4 * m + j] * inv);
    }
    *(short4v*)(outb + obase + m * 8) = ov0;
    *(short4v*)(outb + obase + 32 + m * 8) = ov1;
  }
}

extern "C" void kernel_launch(void* const* d_in, const int* in_sizes, int n_in,
                              void* d_out, int out_size, void* d_ws, size_t ws_size,
                              hipStream_t stream) {
  const float* x      = (const float*)d_in[0];
  const float* pos    = (const float*)d_in[1];
  const float* W_qkv  = (const float*)d_in[2];
  const float* b_qkv  = (const float*)d_in[3];
  const float* W_proj = (const float*)d_in[4];
  const float* b_proj = (const float*)d_in[5];
  float* out = (float*)d_out;

  char* ws = (char*)d_ws;
  short* A       = (short*)(ws);                  // 12,582,912 (consumed by gemm<1>)
  short* attnbuf = (short*)(ws);                  // alias of A (written after)
  short* Bt      = (short*)(ws + 12582912);       //  3,538,944
  short* wpt     = (short*)(ws + 16121856);       //  1,179,648
  short* qbuf    = (short*)(ws + 17301504);       // 12,582,912
  short* kbuf    = (short*)(ws + 29884416);       // 12,582,912
  short* vtbuf   = (short*)(ws + 42467328);       // 12,582,912
  short* posb    = (short*)(ws + 55050240);       // 25,165,824
  // total: 80,216,064 bytes

  prep_x_kernel<<<6144, 256, 0, stream>>>(x, A);
  prep_w_kernel<<<dim3(12, 36), 256, 0, stream>>>(W_qkv, Bt);
  prep_wp_kernel<<<dim3(12, 12), 256, 0, stream>>>(W_proj, wpt);
  prep_pos_kernel<<<6144, 256, 0, stream>>>(pos, posb);
  gemm_kernel<1><<<768, 512, 0, stream>>>(A, Bt, b_qkv,
                                          qbuf, kbuf, vtbuf, nullptr);
  attn_kernel<<<768, 256, 0, stream>>>(qbuf, kbuf, vtbuf, posb, attnbuf);
  gemm_kernel<2><<<256, 512, 0, stream>>>(attnbuf, wpt, b_proj,
                                          nullptr, nullptr, nullptr, out);
}